// Round 9
// baseline (512.356 us; speedup 1.0000x reference)
//
#include <hip/hip_runtime.h>
#include <cstdint>
#include <cstddef>

// GCN: 4x GCNConv (512->256->128->64->32) + mean-pool + 2-layer MLP.
// Round 9: layer-1 GEMM gets a 3-deep pipeline (B triple-buffered, A
// double-buffered via reg-split) with raw s_barrier + counted vmcnt(8) —
// never draining vmcnt in the main loop. Layers 2-4 keep the round-8 kernel.

typedef __attribute__((ext_vector_type(8))) short s16x8;
typedef __attribute__((ext_vector_type(4))) float f32x4;

// fp32 -> (bf16 hi, bf16 lo) by truncation; lo captures the truncation error.
__device__ __forceinline__ short2 split2(float f) {
    union { float f; unsigned u; } c; c.f = f;
    short hi = (short)(c.u >> 16);
    union { unsigned u; float f; } h; h.u = c.u & 0xffff0000u;
    union { float f; unsigned u; } r; r.f = f - h.f;
    short lo = (short)(r.u >> 16);
    return make_short2(hi, lo);
}

// async 16B global -> LDS (wave-uniform LDS base; HW adds lane*16)
__device__ __forceinline__ void gload16(const void* g, void* l) {
    __builtin_amdgcn_global_load_lds(
        (const __attribute__((address_space(1))) unsigned int*)g,
        (__attribute__((address_space(3))) unsigned int*)l, 16, 0, 0);
}

// ---------------- CSR build ----------------

__global__ void k_count(const int* __restrict__ dst, int E, int* __restrict__ cnt) {
    int e = blockIdx.x * blockDim.x + threadIdx.x;
    if (e < E) atomicAdd(&cnt[dst[e]], 1);
}

__global__ void k_dinv(const int* __restrict__ cnt, int n, float* __restrict__ dinv) {
    int i = blockIdx.x * blockDim.x + threadIdx.x;
    if (i < n) dinv[i] = rsqrtf((float)(cnt[i] + 1));
}

__global__ void k_scan_sums(const int* __restrict__ cnt, int n, int* __restrict__ bsum) {
    __shared__ int s[256];
    int t = threadIdx.x;
    int base = blockIdx.x * 4096 + t * 16;
    int sum = 0;
#pragma unroll
    for (int j = 0; j < 16; ++j) { int i = base + j; if (i < n) sum += cnt[i]; }
    s[t] = sum;
    __syncthreads();
    for (int off = 128; off > 0; off >>= 1) {
        if (t < off) s[t] += s[t + off];
        __syncthreads();
    }
    if (t == 0) bsum[blockIdx.x] = s[0];
}

__global__ void k_scan_offsets(const int* __restrict__ bsum, int nb,
                               int* __restrict__ boff, int* __restrict__ totalp) {
    int t = threadIdx.x;   // 64 threads
    int v = (t < nb) ? bsum[t] : 0;
    int x = v;
    for (int off = 1; off < 64; off <<= 1) {
        int y = __shfl_up(x, off);
        if (t >= off) x += y;
    }
    if (t < nb) boff[t] = x - v;
    if (t == 63) *totalp = x;
}

__global__ void k_scan_final(const int* __restrict__ cnt, int n,
                             const int* __restrict__ boff, int* __restrict__ row_ptr) {
    __shared__ int s[256];
    int t = threadIdx.x;
    int base = blockIdx.x * 4096 + t * 16;
    int v[16]; int sum = 0;
#pragma unroll
    for (int j = 0; j < 16; ++j) { int i = base + j; v[j] = (i < n) ? cnt[i] : 0; sum += v[j]; }
    s[t] = sum;
    __syncthreads();
    for (int off = 1; off < 256; off <<= 1) {
        int y = (t >= off) ? s[t - off] : 0;
        __syncthreads();
        s[t] += y;
        __syncthreads();
    }
    int run = boff[blockIdx.x] + ((t == 0) ? 0 : s[t - 1]);
#pragma unroll
    for (int j = 0; j < 16; ++j) {
        int i = base + j;
        if (i < n) row_ptr[i] = run;
        run += v[j];
    }
}

__global__ void k_fill(const int* __restrict__ src, const int* __restrict__ dst, int E,
                       const int* __restrict__ row_ptr, int* __restrict__ cursor,
                       int* __restrict__ csr_src) {
    int e = blockIdx.x * blockDim.x + threadIdx.x;
    if (e >= E) return;
    int d = dst[e];
    int p = atomicAdd(&cursor[d], 1);
    csr_src[row_ptr[d] + p] = src[e];
}

// ---------------- weight pre-split: w[K][N] fp32 -> Bt planes [N][K] bf16 ----------------

__global__ void k_split_w(const float* __restrict__ w, int N, int total, int kshift,
                          unsigned short* __restrict__ th, unsigned short* __restrict__ tl) {
    int idx = blockIdx.x * blockDim.x + threadIdx.x;
    if (idx >= total) return;
    int nn = idx >> kshift;
    int k  = idx & ((1 << kshift) - 1);
    short2 p = split2(w[(size_t)k * N + nn]);
    th[idx] = (unsigned short)p.x;
    tl[idx] = (unsigned short)p.y;
}

// ---------------- layer-1 GEMM: 3-deep pipeline, counted vmcnt ----------------
// C[M,256] = x[M,512] @ W1[512,256]. 256 thr / 4 waves (2x2), BM=BN=128, BK=32.
// B: LDS triple-buffer, loads for t+2 issued at iter t (2 iters of flight).
// A: x fp32 -> regs (issued at iter t for t+2) -> split -> ds_write at end of
// iter t+1 into A double-buffer. One raw s_barrier per K-step preceded by
// s_waitcnt vmcnt(8) lgkmcnt(0): the 8 = X(t+1)[4] + SB(t+1)[4] stay in
// flight; in-order vmcnt retirement => tile t's loads complete.
// Buffers touched concurrently: read t%3/t&1, write A (t+1)&1, write B
// (t+2)%3 — all distinct.  LDS = 2*16KB (A) + 3*16KB (B) = 80KB dynamic.

__global__ __launch_bounds__(256)
void k_gemm1(const float* __restrict__ A32,
             const unsigned short* __restrict__ Bth, const unsigned short* __restrict__ Btl,
             float* __restrict__ C, int M) {
    constexpr int K = 512, KT = 16;
    constexpr int APL = 128 * 64;          // 8KB per A plane (hi or lo)
    constexpr int ABUF = 2 * APL;          // 16KB per A buffer
    constexpr int BPL = 128 * 64;          // 8KB per B plane
    constexpr int BBUF = 2 * BPL;          // 16KB per B buffer
    extern __shared__ __attribute__((aligned(16))) char lds[];   // 80KB
    char* aB0 = lds;
    char* aB1 = lds + ABUF;
    char* bB0 = lds + 2 * ABUF;
    char* bB1 = bB0 + BBUF;
    char* bB2 = bB1 + BBUF;
    char* aB[2] = {aB0, aB1};
    char* bB[3] = {bB0, bB1, bB2};

    const int tid  = threadIdx.x;
    const int lane = tid & 63;
    const int w    = tid >> 6;
    const int wm   = w & 1;
    const int wn   = w >> 1;
    const int brow = blockIdx.y * 128;
    const int bcol = blockIdx.x * 128;
    const int l15  = lane & 15;
    const int kb   = (lane >> 4) * 16;

    // A reg-staging geometry (proven round-8 mapping)
    const int arow  = tid >> 1;
    const int ahalf = tid & 1;
    int ag = brow + arow; if (ag > M - 1) ag = M - 1;   // clamp: dup rows only feed C rows >= M
    const float* xrow = A32 + (size_t)ag * K + ahalf * 16;
    const int vq = (arow >> 1) & 3;
    const int q0 = ((2 * ahalf) ^ vq) * 16;
    const int q1 = ((2 * ahalf + 1) ^ vq) * 16;

    f32x4 acc[4][4];
#pragma unroll
    for (int i = 0; i < 4; ++i)
#pragma unroll
        for (int j = 0; j < 4; ++j) acc[i][j] = (f32x4){0.f, 0.f, 0.f, 0.f};

    float4 xr[2][4];   // ping-pong x regs (statically indexed under full unroll)

    auto X = [&](int t, int p) {
        const float4* q = (const float4*)(xrow + t * 32);
        xr[p][0] = q[0]; xr[p][1] = q[1]; xr[p][2] = q[2]; xr[p][3] = q[3];
    };
    auto SB = [&](char* bbuf, int t) {
#pragma unroll
        for (int u = 0; u < 4; ++u) {
            int id = w + u * 4;                 // 0..15
            int hi = (id < 8) ? 1 : 0;
            int s  = hi ? id : id - 8;
            int p  = s * 64 + lane;
            int kq = (p ^ ((p >> 3) & 3)) & 3;
            int col = p >> 2;
            const unsigned short* gs = (hi ? Bth : Btl) + (size_t)(bcol + col) * K + t * 32 + kq * 8;
            gload16(gs, (hi ? bbuf : bbuf + BPL) + s * 1024);
        }
    };
    auto WA = [&](char* abuf, int p) {
        float v[16] = {xr[p][0].x, xr[p][0].y, xr[p][0].z, xr[p][0].w,
                       xr[p][1].x, xr[p][1].y, xr[p][1].z, xr[p][1].w,
                       xr[p][2].x, xr[p][2].y, xr[p][2].z, xr[p][2].w,
                       xr[p][3].x, xr[p][3].y, xr[p][3].z, xr[p][3].w};
        s16x8 h0, h1, l0, l1;
#pragma unroll
        for (int j = 0; j < 8; ++j) { short2 q = split2(v[j]);     h0[j] = q.x; l0[j] = q.y; }
#pragma unroll
        for (int j = 0; j < 8; ++j) { short2 q = split2(v[8 + j]); h1[j] = q.x; l1[j] = q.y; }
        *(s16x8*)(abuf + arow * 64 + q0)       = h0;
        *(s16x8*)(abuf + arow * 64 + q1)       = h1;
        *(s16x8*)(abuf + APL + arow * 64 + q0) = l0;
        *(s16x8*)(abuf + APL + arow * 64 + q1) = l1;
    };
    auto MM = [&](char* abuf, char* bbuf) {
        char* sAh = abuf;
        char* sAl = abuf + APL;
        char* sBh = bbuf;
        char* sBl = bbuf + BPL;
        s16x8 fah[4], fam[4];
#pragma unroll
        for (int i = 0; i < 4; ++i) {
            int row = wm * 64 + i * 16 + l15;
            int o = row * 64 + (kb ^ (((row >> 1) & 3) << 4));
            fah[i] = *(const s16x8*)(sAh + o);
            fam[i] = *(const s16x8*)(sAl + o);
        }
#pragma unroll
        for (int j = 0; j < 4; ++j) {
            int col = wn * 64 + j * 16 + l15;
            int o = col * 64 + (kb ^ (((col >> 1) & 3) << 4));
            s16x8 fbh = *(const s16x8*)(sBh + o);
            s16x8 fbm = *(const s16x8*)(sBl + o);
#pragma unroll
            for (int i = 0; i < 4; ++i) {
                acc[i][j] = __builtin_amdgcn_mfma_f32_16x16x32_bf16(fah[i], fbh, acc[i][j], 0, 0, 0);
                acc[i][j] = __builtin_amdgcn_mfma_f32_16x16x32_bf16(fam[i], fbh, acc[i][j], 0, 0, 0);
                acc[i][j] = __builtin_amdgcn_mfma_f32_16x16x32_bf16(fah[i], fbm, acc[i][j], 0, 0, 0);
            }
        }
    };

    // prologue: X(0), SB(0), X(1), SB(1) (issue order matters for vmcnt math)
    X(0, 0);
    SB(bB[0], 0);
    X(1, 1);
    SB(bB[1], 1);
    WA(aB[0], 0);          // dep-waits X(0) only (counted, auto)

#pragma unroll
    for (int t = 0; t < KT; ++t) {
        if (t + 1 < KT) {
            asm volatile("s_waitcnt vmcnt(8) lgkmcnt(0)" ::: "memory");
        } else {
            asm volatile("s_waitcnt vmcnt(0) lgkmcnt(0)" ::: "memory");
        }
        __builtin_amdgcn_sched_barrier(0);
        __builtin_amdgcn_s_barrier();
        if (t + 2 < KT) {               // issue loads for t+2 (2 iterations of flight)
            X(t + 2, t & 1);
            SB(bB[(t + 2) % 3], t + 2);
        }
        MM(aB[t & 1], bB[t % 3]);
        if (t + 1 < KT) WA(aB[(t + 1) & 1], (t + 1) & 1);   // consumes X(t+1)
    }

    // C/D layout: col = lane&15, row = (lane>>4)*4 + reg
#pragma unroll
    for (int i = 0; i < 4; ++i) {
#pragma unroll
        for (int r = 0; r < 4; ++r) {
            int row = brow + wm * 64 + i * 16 + (lane >> 4) * 4 + r;
            if (row >= M) continue;
#pragma unroll
            for (int j = 0; j < 4; ++j) {
                int col = bcol + wn * 64 + j * 16 + l15;
                C[(size_t)row * 256 + col] = acc[i][j][r];
            }
        }
    }
}

// ---------------- 2-phase dbuf split-bf16 MFMA GEMM (layers 2-4) ----------------

template <int FN>
__global__ __launch_bounds__(256)
void k_gemm(const unsigned short* __restrict__ Ah, const unsigned short* __restrict__ Al,
            const unsigned short* __restrict__ Bth, const unsigned short* __restrict__ Btl,
            float* __restrict__ C, int M, int K, int N) {
    constexpr int FM = 4;
    constexpr int BM = 128;
    constexpr int BN = FN * 32;
    constexpr int ABYTES = BM * 64;
    constexpr int BBYTES = BN * 64;
    constexpr int BUF = 2 * ABYTES + 2 * BBYTES;
    __shared__ char lds[2 * BUF];

    const int tid  = threadIdx.x;
    const int lane = tid & 63;
    const int w    = tid >> 6;
    const int wm   = w & 1;
    const int wn   = w >> 1;
    const int brow = blockIdx.y * BM;
    const int bcol = blockIdx.x * BN;
    const int l15  = lane & 15;
    const int kb   = (lane >> 4) * 16;

    f32x4 acc[FM][FN];
#pragma unroll
    for (int i = 0; i < FM; ++i)
#pragma unroll
        for (int j = 0; j < FN; ++j) acc[i][j] = (f32x4){0.f, 0.f, 0.f, 0.f};

    auto stageA = [&](char* base, int k0) {
#pragma unroll
        for (int u = 0; u < 4; ++u) {
            int id = w + u * 4;
            int hi = (id < 8) ? 1 : 0;
            int s  = hi ? id : id - 8;
            int p  = s * 64 + lane;
            int kq = (p ^ ((p >> 3) & 3)) & 3;
            int row = p >> 2;
            const unsigned short* gs = (hi ? Ah : Al) + (size_t)(brow + row) * K + k0 + kq * 8;
            gload16(gs, base + (hi ? 0 : ABYTES) + s * 1024);
        }
    };
    auto stageB = [&](char* base, int k0) {
        char* sBh = base + 2 * ABYTES;
        char* sBl = sBh + BBYTES;
#pragma unroll
        for (int u = 0; u < BN / 32; ++u) {
            int id = w + u * 4;
            int hi = (id < BN / 16) ? 1 : 0;
            int s  = hi ? id : id - BN / 16;
            int p  = s * 64 + lane;
            int kq = (p ^ ((p >> 3) & 3)) & 3;
            int col = p >> 2;
            const unsigned short* gs = (hi ? Bth : Btl) + (size_t)(bcol + col) * K + k0 + kq * 8;
            gload16(gs, (hi ? sBh : sBl) + s * 1024);
        }
    };

    char* cur = lds;
    char* nxt = lds + BUF;
    stageB(cur, 0);
    stageA(cur, 0);
    __syncthreads();

    const int KT = K / 32;
    for (int t = 0; t < KT; ++t) {
        const int k1 = (t + 1) * 32;
        if (t + 1 < KT) {
            stageB(nxt, k1);
            stageA(nxt, k1);
        }
        {
            char* sAh = cur;
            char* sAl = cur + ABYTES;
            char* sBh = cur + 2 * ABYTES;
            char* sBl = sBh + BBYTES;
            s16x8 fah[FM], fam[FM];
#pragma unroll
            for (int i = 0; i < FM; ++i) {
                int row = wm * 64 + i * 16 + l15;
                int o = row * 64 + (kb ^ (((row >> 1) & 3) << 4));
                fah[i] = *(const s16x8*)(sAh + o);
                fam[i] = *(const s16x8*)(sAl + o);
            }
#pragma unroll
            for (int j = 0; j < FN; ++j) {
                int col = wn * FN * 16 + j * 16 + l15;
                int o = col * 64 + (kb ^ (((col >> 1) & 3) << 4));
                s16x8 fbh = *(const s16x8*)(sBh + o);
                s16x8 fbm = *(const s16x8*)(sBl + o);
#pragma unroll
                for (int i = 0; i < FM; ++i) {
                    acc[i][j] = __builtin_amdgcn_mfma_f32_16x16x32_bf16(fah[i], fbh, acc[i][j], 0, 0, 0);
                    acc[i][j] = __builtin_amdgcn_mfma_f32_16x16x32_bf16(fam[i], fbh, acc[i][j], 0, 0, 0);
                    acc[i][j] = __builtin_amdgcn_mfma_f32_16x16x32_bf16(fah[i], fbm, acc[i][j], 0, 0, 0);
                }
            }
        }
        __syncthreads();
        char* tmp = cur; cur = nxt; nxt = tmp;
    }

#pragma unroll
    for (int i = 0; i < FM; ++i) {
#pragma unroll
        for (int r = 0; r < 4; ++r) {
            int row = brow + wm * 64 + i * 16 + (lane >> 4) * 4 + r;
            if (row >= M) continue;
#pragma unroll
            for (int j = 0; j < FN; ++j) {
                int col = bcol + wn * FN * 16 + j * 16 + l15;
                C[(size_t)row * N + col] = acc[i][j][r];
            }
        }
    }
}

// ---------------- aggregation (+bias, relu) -> bf16 hi/lo planes ----------------

__global__ void k_agg_split(const float4* __restrict__ h, const int* __restrict__ row_ptr,
                            const int* __restrict__ csr_src, const float* __restrict__ dinv,
                            const float* __restrict__ bias,
                            unsigned short* __restrict__ oh, unsigned short* __restrict__ ol,
                            int n, int f_shift) {
    int idx = blockIdx.x * blockDim.x + threadIdx.x;
    int dout4 = 1 << f_shift;
    int total = n << f_shift;
    if (idx >= total) return;
    int i = idx >> f_shift;
    int f = idx & (dout4 - 1);

    float di = dinv[i];
    float4 hv = h[(size_t)i * dout4 + f];
    float4 acc;
    acc.x = hv.x * di; acc.y = hv.y * di; acc.z = hv.z * di; acc.w = hv.w * di;

    int s0 = row_ptr[i], s1 = row_ptr[i + 1];
    for (int e = s0; e < s1; ++e) {
        int s = csr_src[e];
        float ds = dinv[s];
        float4 v = h[(size_t)s * dout4 + f];
        acc.x += v.x * ds; acc.y += v.y * ds; acc.z += v.z * ds; acc.w += v.w * ds;
    }
    const float4* b4 = (const float4*)bias;
    float4 b = b4[f];
    float4 o;
    o.x = fmaxf(acc.x * di + b.x, 0.f);
    o.y = fmaxf(acc.y * di + b.y, 0.f);
    o.z = fmaxf(acc.z * di + b.z, 0.f);
    o.w = fmaxf(acc.w * di + b.w, 0.f);

    short2 p0 = split2(o.x), p1 = split2(o.y), p2 = split2(o.z), p3 = split2(o.w);
    size_t base = ((size_t)i << f_shift << 2) + f * 4;
    *(ushort4*)(oh + base) = make_ushort4((unsigned short)p0.x, (unsigned short)p1.x,
                                          (unsigned short)p2.x, (unsigned short)p3.x);
    *(ushort4*)(ol + base) = make_ushort4((unsigned short)p0.y, (unsigned short)p1.y,
                                          (unsigned short)p2.y, (unsigned short)p3.y);
}

// ---------------- aggregation (+bias), fp32 out (layer 4) ----------------

__global__ void k_agg(const float4* __restrict__ h, const int* __restrict__ row_ptr,
                      const int* __restrict__ csr_src, const float* __restrict__ dinv,
                      const float* __restrict__ bias, float4* __restrict__ out,
                      int n, int f_shift) {
    int idx = blockIdx.x * blockDim.x + threadIdx.x;
    int dout4 = 1 << f_shift;
    int total = n << f_shift;
    if (idx >= total) return;
    int i = idx >> f_shift;
    int f = idx & (dout4 - 1);

    float di = dinv[i];
    float4 hv = h[(size_t)i * dout4 + f];
    float4 acc;
    acc.x = hv.x * di; acc.y = hv.y * di; acc.z = hv.z * di; acc.w = hv.w * di;

    int s0 = row_ptr[i], s1 = row_ptr[i + 1];
    for (int e = s0; e < s1; ++e) {
        int s = csr_src[e];
        float ds = dinv[s];
        float4 v = h[(size_t)s * dout4 + f];
        acc.x += v.x * ds; acc.y += v.y * ds; acc.z += v.z * ds; acc.w += v.w * ds;
    }
    const float4* b4 = (const float4*)bias;
    float4 b = b4[f];
    float4 o;
    o.x = acc.x * di + b.x;
    o.y = acc.y * di + b.y;
    o.z = acc.z * di + b.z;
    o.w = acc.w * di + b.w;
    out[(size_t)i * dout4 + f] = o;
}

// ---------------- mean pool per graph (batch sorted) ----------------

__global__ void k_pool(const float* __restrict__ h, const int* __restrict__ batch,
                       int n, float* __restrict__ pooled) {
    int g = blockIdx.x;
    int start, end;
    {
        int lo = 0, hi = n;
        while (lo < hi) { int mid = (lo + hi) >> 1; if (batch[mid] < g) lo = mid + 1; else hi = mid; }
        start = lo;
        lo = start; hi = n;
        while (lo < hi) { int mid = (lo + hi) >> 1; if (batch[mid] < g + 1) lo = mid + 1; else hi = mid; }
        end = lo;
    }
    int f = threadIdx.x & 31;
    int sub = threadIdx.x >> 5;
    float s = 0.f;
    for (int i = start + sub; i < end; i += 8) s += h[(size_t)i * 32 + f];
    __shared__ float red[8][32];
    red[sub][f] = s;
    __syncthreads();
    if (sub == 0) {
        float t = 0.f;
#pragma unroll
        for (int k = 0; k < 8; ++k) t += red[k][f];
        int c = end - start;
        pooled[g * 32 + f] = t / (float)(c > 0 ? c : 1);
    }
}

// ---------------- tiny MLP head ----------------

__global__ void k_mlp(const float* __restrict__ pooled, const float* __restrict__ lw1,
                      const float* __restrict__ lb1, const float* __restrict__ lw2,
                      const float* __restrict__ lb2, float* __restrict__ out, int g_count) {
    int g = threadIdx.x;
    if (g >= g_count) return;
    float p[32];
#pragma unroll
    for (int k = 0; k < 32; ++k) p[k] = pooled[g * 32 + k];
    float hmid[16];
#pragma unroll
    for (int j = 0; j < 16; ++j) {
        float s = lb1[j];
#pragma unroll
        for (int k = 0; k < 32; ++k) s += p[k] * lw1[k * 16 + j];
        hmid[j] = fmaxf(s, 0.f);
    }
#pragma unroll
    for (int o = 0; o < 2; ++o) {
        float s = lb2[o];
#pragma unroll
        for (int k = 0; k < 16; ++k) s += hmid[k] * lw2[k * 2 + o];
        out[g * 2 + o] = s;
    }
}

// ---------------- launch ----------------

extern "C" void kernel_launch(void* const* d_in, const int* in_sizes, int n_in,
                              void* d_out, int out_size, void* d_ws, size_t ws_size,
                              hipStream_t stream) {
    const float* x     = (const float*)d_in[0];
    const int*   ei    = (const int*)d_in[1];
    const int*   batch = (const int*)d_in[2];
    const float* w1 = (const float*)d_in[3];  const float* b1 = (const float*)d_in[4];
    const float* w2 = (const float*)d_in[5];  const float* b2 = (const float*)d_in[6];
    const float* w3 = (const float*)d_in[7];  const float* b3 = (const float*)d_in[8];
    const float* w4 = (const float*)d_in[9];  const float* b4 = (const float*)d_in[10];
    const float* lw1 = (const float*)d_in[11]; const float* lb1 = (const float*)d_in[12];
    const float* lw2 = (const float*)d_in[13]; const float* lb2 = (const float*)d_in[14];
    float* out = (float*)d_out;

    const int n = in_sizes[0] / 512;   // 100000
    const int E = in_sizes[1] / 2;     // 320000
    const int G = 64;

    const int* src = ei;
    const int* dst = ei + E;

    char* ws = (char*)d_ws;
    size_t off = 0;
    auto alloc = [&](size_t bytes) -> void* {
        void* p = ws + off;
        off = (off + bytes + 255) & ~((size_t)255);
        return p;
    };
    float*          bufA = (float*)alloc((size_t)n * 256 * sizeof(float));  // GEMM out
    unsigned short* pAh  = (unsigned short*)alloc((size_t)n * 256 * 2);     // layer planes
    unsigned short* pAl  = (unsigned short*)alloc((size_t)n * 256 * 2);
    int*   cnt     = (int*)alloc((size_t)n * sizeof(int));
    int*   row_ptr = (int*)alloc((size_t)(n + 1) * sizeof(int));
    int*   cursor  = (int*)alloc((size_t)n * sizeof(int));
    int*   csr     = (int*)alloc((size_t)E * sizeof(int));
    float* dinv    = (float*)alloc((size_t)n * sizeof(float));
    float* pooled  = (float*)alloc((size_t)G * 32 * sizeof(float));
    int*   bsum    = (int*)alloc(64 * sizeof(int));
    int*   boff    = (int*)alloc(64 * sizeof(int));
    unsigned short* w1h = (unsigned short*)alloc(256 * 512 * 2);
    unsigned short* w1l = (unsigned short*)alloc(256 * 512 * 2);
    unsigned short* w2h = (unsigned short*)alloc(128 * 256 * 2);
    unsigned short* w2l = (unsigned short*)alloc(128 * 256 * 2);
    unsigned short* w3h = (unsigned short*)alloc(64 * 128 * 2);
    unsigned short* w3l = (unsigned short*)alloc(64 * 128 * 2);
    unsigned short* w4h = (unsigned short*)alloc(32 * 64 * 2);
    unsigned short* w4l = (unsigned short*)alloc(32 * 64 * 2);
    // layer-4 fp32 agg output parked in pAl beyond the live d=64 plane region
    float* bufB = (float*)(pAl + (size_t)n * 64);
    (void)ws_size;

    // allow 80KB dynamic LDS for the pipelined layer-1 GEMM
    hipFuncSetAttribute((const void*)k_gemm1,
                        hipFuncAttributeMaxDynamicSharedMemorySize, 80 * 1024);

    hipMemsetAsync(cnt, 0, (size_t)n * sizeof(int), stream);
    hipMemsetAsync(cursor, 0, (size_t)n * sizeof(int), stream);

    // weight pre-split (tiny)
    k_split_w<<<(256 * 512 + 255) / 256, 256, 0, stream>>>(w1, 256, 256 * 512, 9, w1h, w1l);
    k_split_w<<<(128 * 256 + 255) / 256, 256, 0, stream>>>(w2, 128, 128 * 256, 8, w2h, w2l);
    k_split_w<<<(64 * 128 + 255) / 256, 256, 0, stream>>>(w3, 64, 64 * 128, 7, w3h, w3l);
    k_split_w<<<(32 * 64 + 255) / 256, 256, 0, stream>>>(w4, 32, 32 * 64, 6, w4h, w4l);

    const int nscan = (n + 4095) / 4096;
    k_count<<<(E + 255) / 256, 256, 0, stream>>>(dst, E, cnt);
    k_dinv <<<(n + 255) / 256, 256, 0, stream>>>(cnt, n, dinv);
    k_scan_sums   <<<nscan, 256, 0, stream>>>(cnt, n, bsum);
    k_scan_offsets<<<1, 64, 0, stream>>>(bsum, nscan, boff, row_ptr + n);
    k_scan_final  <<<nscan, 256, 0, stream>>>(cnt, n, boff, row_ptr);
    k_fill<<<(E + 255) / 256, 256, 0, stream>>>(src, dst, E, row_ptr, cursor, csr);

    const int gy = (n + 127) / 128;   // 782, BM=128

    // layer 1: [n,512]@[512,256], BN=128, pipelined kernel, x split in-kernel
    k_gemm1<<<dim3(2, gy), 256, 80 * 1024, stream>>>(x, w1h, w1l, bufA, n);
    k_agg_split<<<((size_t)n * 64 + 255) / 256, 256, 0, stream>>>(
        (const float4*)bufA, row_ptr, csr, dinv, b1, pAh, pAl, n, 6);

    // layer 2: [n,256]@[256,128]
    k_gemm<4><<<dim3(1, gy), 256, 0, stream>>>(pAh, pAl, w2h, w2l, bufA, n, 256, 128);
    k_agg_split<<<((size_t)n * 32 + 255) / 256, 256, 0, stream>>>(
        (const float4*)bufA, row_ptr, csr, dinv, b2, pAh, pAl, n, 5);

    // layer 3: [n,128]@[128,64]
    k_gemm<2><<<dim3(1, gy), 256, 0, stream>>>(pAh, pAl, w3h, w3l, bufA, n, 128, 64);
    k_agg_split<<<((size_t)n * 16 + 255) / 256, 256, 0, stream>>>(
        (const float4*)bufA, row_ptr, csr, dinv, b3, pAh, pAl, n, 4);

    // layer 4: [n,64]@[64,32] (no relu)
    k_gemm<1><<<dim3(1, gy), 256, 0, stream>>>(pAh, pAl, w4h, w4l, bufA, n, 64, 32);
    k_agg<<<((size_t)n * 8 + 255) / 256, 256, 0, stream>>>(
        (const float4*)bufA, row_ptr, csr, dinv, b4, (float4*)bufB, n, 3);

    k_pool<<<G, 256, 0, stream>>>(bufB, batch, n, pooled);
    k_mlp<<<1, 64, 0, stream>>>(pooled, lw1, lb1, lw2, lb2, out, G);
}

// Round 10
// 504.795 us; speedup vs baseline: 1.0150x; 1.0150x over previous
//
#include <hip/hip_runtime.h>
#include <cstdint>
#include <cstddef>

// GCN: 4x GCNConv (512->256->128->64->32) + mean-pool + 2-layer MLP.
// Round 10: GEMM1 = single-buffer 32KB LDS (5 blocks/CU) + in-kernel x split.
// Evidence: blocks/CU beats pipeline depth (r6:32KB=124 < r8:64KB=133 <
// r9:80KB=143). Layers 2-4 keep the round-8 dbuf kernel.

typedef __attribute__((ext_vector_type(8))) short s16x8;
typedef __attribute__((ext_vector_type(4))) float f32x4;

// fp32 -> (bf16 hi, bf16 lo) by truncation; lo captures the truncation error.
__device__ __forceinline__ short2 split2(float f) {
    union { float f; unsigned u; } c; c.f = f;
    short hi = (short)(c.u >> 16);
    union { unsigned u; float f; } h; h.u = c.u & 0xffff0000u;
    union { float f; unsigned u; } r; r.f = f - h.f;
    short lo = (short)(r.u >> 16);
    return make_short2(hi, lo);
}

// async 16B global -> LDS (wave-uniform LDS base; HW adds lane*16)
__device__ __forceinline__ void gload16(const void* g, void* l) {
    __builtin_amdgcn_global_load_lds(
        (const __attribute__((address_space(1))) unsigned int*)g,
        (__attribute__((address_space(3))) unsigned int*)l, 16, 0, 0);
}

// ---------------- CSR build ----------------

__global__ void k_count(const int* __restrict__ dst, int E, int* __restrict__ cnt) {
    int e = blockIdx.x * blockDim.x + threadIdx.x;
    if (e < E) atomicAdd(&cnt[dst[e]], 1);
}

__global__ void k_dinv(const int* __restrict__ cnt, int n, float* __restrict__ dinv) {
    int i = blockIdx.x * blockDim.x + threadIdx.x;
    if (i < n) dinv[i] = rsqrtf((float)(cnt[i] + 1));
}

__global__ void k_scan_sums(const int* __restrict__ cnt, int n, int* __restrict__ bsum) {
    __shared__ int s[256];
    int t = threadIdx.x;
    int base = blockIdx.x * 4096 + t * 16;
    int sum = 0;
#pragma unroll
    for (int j = 0; j < 16; ++j) { int i = base + j; if (i < n) sum += cnt[i]; }
    s[t] = sum;
    __syncthreads();
    for (int off = 128; off > 0; off >>= 1) {
        if (t < off) s[t] += s[t + off];
        __syncthreads();
    }
    if (t == 0) bsum[blockIdx.x] = s[0];
}

__global__ void k_scan_offsets(const int* __restrict__ bsum, int nb,
                               int* __restrict__ boff, int* __restrict__ totalp) {
    int t = threadIdx.x;   // 64 threads
    int v = (t < nb) ? bsum[t] : 0;
    int x = v;
    for (int off = 1; off < 64; off <<= 1) {
        int y = __shfl_up(x, off);
        if (t >= off) x += y;
    }
    if (t < nb) boff[t] = x - v;
    if (t == 63) *totalp = x;
}

__global__ void k_scan_final(const int* __restrict__ cnt, int n,
                             const int* __restrict__ boff, int* __restrict__ row_ptr) {
    __shared__ int s[256];
    int t = threadIdx.x;
    int base = blockIdx.x * 4096 + t * 16;
    int v[16]; int sum = 0;
#pragma unroll
    for (int j = 0; j < 16; ++j) { int i = base + j; v[j] = (i < n) ? cnt[i] : 0; sum += v[j]; }
    s[t] = sum;
    __syncthreads();
    for (int off = 1; off < 256; off <<= 1) {
        int y = (t >= off) ? s[t - off] : 0;
        __syncthreads();
        s[t] += y;
        __syncthreads();
    }
    int run = boff[blockIdx.x] + ((t == 0) ? 0 : s[t - 1]);
#pragma unroll
    for (int j = 0; j < 16; ++j) {
        int i = base + j;
        if (i < n) row_ptr[i] = run;
        run += v[j];
    }
}

__global__ void k_fill(const int* __restrict__ src, const int* __restrict__ dst, int E,
                       const int* __restrict__ row_ptr, int* __restrict__ cursor,
                       int* __restrict__ csr_src) {
    int e = blockIdx.x * blockDim.x + threadIdx.x;
    if (e >= E) return;
    int d = dst[e];
    int p = atomicAdd(&cursor[d], 1);
    csr_src[row_ptr[d] + p] = src[e];
}

// ---------------- weight pre-split: w[K][N] fp32 -> Bt planes [N][K] bf16 ----------------

__global__ void k_split_w(const float* __restrict__ w, int N, int total, int kshift,
                          unsigned short* __restrict__ th, unsigned short* __restrict__ tl) {
    int idx = blockIdx.x * blockDim.x + threadIdx.x;
    if (idx >= total) return;
    int nn = idx >> kshift;
    int k  = idx & ((1 << kshift) - 1);
    short2 p = split2(w[(size_t)k * N + nn]);
    th[idx] = (unsigned short)p.x;
    tl[idx] = (unsigned short)p.y;
}

// ---------------- layer-1 GEMM: single-buffer 32KB, in-kernel x split ----------------
// C[M,256] = x[M,512] @ W1. 256 thr / 4 waves (2x2), BM=BN=128, BK=32.
// Per K-step: barrier1 (staging done) -> issue X(t+1) reg loads -> MFMA(t)
// -> barrier2 (LDS consumed) -> split+ds_write A(t+1) -> issue B(t+1) gloads.
// 32KB LDS => 5 blocks/CU; inter-block TLP covers the drain exposure.
// LDS chunk swizzle: 16B-chunk-in-row q stored at q ^ ((row>>1)&3).

__global__ __launch_bounds__(256)
void k_gemm1(const float* __restrict__ A32,
             const unsigned short* __restrict__ Bth, const unsigned short* __restrict__ Btl,
             float* __restrict__ C, int M) {
    constexpr int K = 512, KT = 16;
    constexpr int APL = 128 * 64;   // 8KB per A plane
    constexpr int BPL = 128 * 64;   // 8KB per B plane
    __shared__ char sA[2 * APL];    // hi, lo
    __shared__ char sB[2 * BPL];

    const int tid  = threadIdx.x;
    const int lane = tid & 63;
    const int w    = tid >> 6;
    const int wm   = w & 1;
    const int wn   = w >> 1;
    const int brow = blockIdx.y * 128;
    const int bcol = blockIdx.x * 128;
    const int l15  = lane & 15;
    const int kb   = (lane >> 4) * 16;

    // A reg-staging geometry (round-8 proven mapping)
    const int arow  = tid >> 1;
    const int ahalf = tid & 1;
    int ag = brow + arow; if (ag > M - 1) ag = M - 1;   // clamp: dup rows only feed C rows >= M
    const float* xrow = A32 + (size_t)ag * K + ahalf * 16;
    const int vq = (arow >> 1) & 3;
    const int q0 = ((2 * ahalf) ^ vq) * 16;
    const int q1 = ((2 * ahalf + 1) ^ vq) * 16;

    f32x4 acc[4][4];
#pragma unroll
    for (int i = 0; i < 4; ++i)
#pragma unroll
        for (int j = 0; j < 4; ++j) acc[i][j] = (f32x4){0.f, 0.f, 0.f, 0.f};

    float4 xr0, xr1, xr2, xr3;   // single X reg set

    auto X = [&](int t) {
        const float4* q = (const float4*)(xrow + t * 32);
        xr0 = q[0]; xr1 = q[1]; xr2 = q[2]; xr3 = q[3];
    };
    auto WA = [&]() {
        float v[16] = {xr0.x, xr0.y, xr0.z, xr0.w, xr1.x, xr1.y, xr1.z, xr1.w,
                       xr2.x, xr2.y, xr2.z, xr2.w, xr3.x, xr3.y, xr3.z, xr3.w};
        s16x8 h0, h1, l0, l1;
#pragma unroll
        for (int j = 0; j < 8; ++j) { short2 q = split2(v[j]);     h0[j] = q.x; l0[j] = q.y; }
#pragma unroll
        for (int j = 0; j < 8; ++j) { short2 q = split2(v[8 + j]); h1[j] = q.x; l1[j] = q.y; }
        *(s16x8*)(sA + arow * 64 + q0)       = h0;
        *(s16x8*)(sA + arow * 64 + q1)       = h1;
        *(s16x8*)(sA + APL + arow * 64 + q0) = l0;
        *(s16x8*)(sA + APL + arow * 64 + q1) = l1;
    };
    auto SB = [&](int t) {
#pragma unroll
        for (int u = 0; u < 4; ++u) {
            int id = w + u * 4;                 // 0..15
            int hi = (id < 8) ? 1 : 0;
            int s  = hi ? id : id - 8;
            int p  = s * 64 + lane;
            int kq = (p ^ ((p >> 3) & 3)) & 3;
            int col = p >> 2;
            const unsigned short* gs = (hi ? Bth : Btl) + (size_t)(bcol + col) * K + t * 32 + kq * 8;
            gload16(gs, (hi ? sB : sB + BPL) + s * 1024);
        }
    };

    // prologue: stage tile 0
    X(0);
    WA();        // waits X(0) via counted vmcnt
    SB(0);

    for (int t = 0; t < KT; ++t) {
        __syncthreads();               // staging of tile t complete (vm+lgkm drain)
        if (t + 1 < KT) X(t + 1);      // issue next x loads; fly during MFMA

        {
            char* sAl = sA + APL;
            char* sBl = sB + BPL;
            s16x8 fah[4], fam[4];
#pragma unroll
            for (int i = 0; i < 4; ++i) {
                int row = wm * 64 + i * 16 + l15;
                int o = row * 64 + (kb ^ (((row >> 1) & 3) << 4));
                fah[i] = *(const s16x8*)(sA + o);
                fam[i] = *(const s16x8*)(sAl + o);
            }
#pragma unroll
            for (int j = 0; j < 4; ++j) {
                int col = wn * 64 + j * 16 + l15;
                int o = col * 64 + (kb ^ (((col >> 1) & 3) << 4));
                s16x8 fbh = *(const s16x8*)(sB + o);
                s16x8 fbm = *(const s16x8*)(sBl + o);
#pragma unroll
                for (int i = 0; i < 4; ++i) {
                    acc[i][j] = __builtin_amdgcn_mfma_f32_16x16x32_bf16(fah[i], fbh, acc[i][j], 0, 0, 0);
                    acc[i][j] = __builtin_amdgcn_mfma_f32_16x16x32_bf16(fam[i], fbh, acc[i][j], 0, 0, 0);
                    acc[i][j] = __builtin_amdgcn_mfma_f32_16x16x32_bf16(fah[i], fbm, acc[i][j], 0, 0, 0);
                }
            }
        }

        __syncthreads();               // tile t fully consumed
        if (t + 1 < KT) {
            WA();                      // split+write A(t+1) (X latency mostly elapsed)
            SB(t + 1);                 // issue B(t+1); drains at next barrier
        }
    }

    // C/D layout: col = lane&15, row = (lane>>4)*4 + reg
#pragma unroll
    for (int i = 0; i < 4; ++i) {
#pragma unroll
        for (int r = 0; r < 4; ++r) {
            int row = brow + wm * 64 + i * 16 + (lane >> 4) * 4 + r;
            if (row >= M) continue;
#pragma unroll
            for (int j = 0; j < 4; ++j) {
                int col = bcol + wn * 64 + j * 16 + l15;
                C[(size_t)row * 256 + col] = acc[i][j][r];
            }
        }
    }
}

// ---------------- 2-phase dbuf split-bf16 MFMA GEMM (layers 2-4) ----------------

template <int FN>
__global__ __launch_bounds__(256)
void k_gemm(const unsigned short* __restrict__ Ah, const unsigned short* __restrict__ Al,
            const unsigned short* __restrict__ Bth, const unsigned short* __restrict__ Btl,
            float* __restrict__ C, int M, int K, int N) {
    constexpr int FM = 4;
    constexpr int BM = 128;
    constexpr int BN = FN * 32;
    constexpr int ABYTES = BM * 64;
    constexpr int BBYTES = BN * 64;
    constexpr int BUF = 2 * ABYTES + 2 * BBYTES;
    __shared__ char lds[2 * BUF];

    const int tid  = threadIdx.x;
    const int lane = tid & 63;
    const int w    = tid >> 6;
    const int wm   = w & 1;
    const int wn   = w >> 1;
    const int brow = blockIdx.y * BM;
    const int bcol = blockIdx.x * BN;
    const int l15  = lane & 15;
    const int kb   = (lane >> 4) * 16;

    f32x4 acc[FM][FN];
#pragma unroll
    for (int i = 0; i < FM; ++i)
#pragma unroll
        for (int j = 0; j < FN; ++j) acc[i][j] = (f32x4){0.f, 0.f, 0.f, 0.f};

    auto stageA = [&](char* base, int k0) {
#pragma unroll
        for (int u = 0; u < 4; ++u) {
            int id = w + u * 4;
            int hi = (id < 8) ? 1 : 0;
            int s  = hi ? id : id - 8;
            int p  = s * 64 + lane;
            int kq = (p ^ ((p >> 3) & 3)) & 3;
            int row = p >> 2;
            const unsigned short* gs = (hi ? Ah : Al) + (size_t)(brow + row) * K + k0 + kq * 8;
            gload16(gs, base + (hi ? 0 : ABYTES) + s * 1024);
        }
    };
    auto stageB = [&](char* base, int k0) {
        char* sBh = base + 2 * ABYTES;
        char* sBl = sBh + BBYTES;
#pragma unroll
        for (int u = 0; u < BN / 32; ++u) {
            int id = w + u * 4;
            int hi = (id < BN / 16) ? 1 : 0;
            int s  = hi ? id : id - BN / 16;
            int p  = s * 64 + lane;
            int kq = (p ^ ((p >> 3) & 3)) & 3;
            int col = p >> 2;
            const unsigned short* gs = (hi ? Bth : Btl) + (size_t)(bcol + col) * K + k0 + kq * 8;
            gload16(gs, (hi ? sBh : sBl) + s * 1024);
        }
    };

    char* cur = lds;
    char* nxt = lds + BUF;
    stageB(cur, 0);
    stageA(cur, 0);
    __syncthreads();

    const int KT = K / 32;
    for (int t = 0; t < KT; ++t) {
        const int k1 = (t + 1) * 32;
        if (t + 1 < KT) {
            stageB(nxt, k1);
            stageA(nxt, k1);
        }
        {
            char* sAh = cur;
            char* sAl = cur + ABYTES;
            char* sBh = cur + 2 * ABYTES;
            char* sBl = sBh + BBYTES;
            s16x8 fah[FM], fam[FM];
#pragma unroll
            for (int i = 0; i < FM; ++i) {
                int row = wm * 64 + i * 16 + l15;
                int o = row * 64 + (kb ^ (((row >> 1) & 3) << 4));
                fah[i] = *(const s16x8*)(sAh + o);
                fam[i] = *(const s16x8*)(sAl + o);
            }
#pragma unroll
            for (int j = 0; j < FN; ++j) {
                int col = wn * FN * 16 + j * 16 + l15;
                int o = col * 64 + (kb ^ (((col >> 1) & 3) << 4));
                s16x8 fbh = *(const s16x8*)(sBh + o);
                s16x8 fbm = *(const s16x8*)(sBl + o);
#pragma unroll
                for (int i = 0; i < FM; ++i) {
                    acc[i][j] = __builtin_amdgcn_mfma_f32_16x16x32_bf16(fah[i], fbh, acc[i][j], 0, 0, 0);
                    acc[i][j] = __builtin_amdgcn_mfma_f32_16x16x32_bf16(fam[i], fbh, acc[i][j], 0, 0, 0);
                    acc[i][j] = __builtin_amdgcn_mfma_f32_16x16x32_bf16(fah[i], fbm, acc[i][j], 0, 0, 0);
                }
            }
        }
        __syncthreads();
        char* tmp = cur; cur = nxt; nxt = tmp;
    }

#pragma unroll
    for (int i = 0; i < FM; ++i) {
#pragma unroll
        for (int r = 0; r < 4; ++r) {
            int row = brow + wm * 64 + i * 16 + (lane >> 4) * 4 + r;
            if (row >= M) continue;
#pragma unroll
            for (int j = 0; j < FN; ++j) {
                int col = bcol + wn * FN * 16 + j * 16 + l15;
                C[(size_t)row * N + col] = acc[i][j][r];
            }
        }
    }
}

// ---------------- aggregation (+bias, relu) -> bf16 hi/lo planes ----------------

__global__ void k_agg_split(const float4* __restrict__ h, const int* __restrict__ row_ptr,
                            const int* __restrict__ csr_src, const float* __restrict__ dinv,
                            const float* __restrict__ bias,
                            unsigned short* __restrict__ oh, unsigned short* __restrict__ ol,
                            int n, int f_shift) {
    int idx = blockIdx.x * blockDim.x + threadIdx.x;
    int dout4 = 1 << f_shift;
    int total = n << f_shift;
    if (idx >= total) return;
    int i = idx >> f_shift;
    int f = idx & (dout4 - 1);

    float di = dinv[i];
    float4 hv = h[(size_t)i * dout4 + f];
    float4 acc;
    acc.x = hv.x * di; acc.y = hv.y * di; acc.z = hv.z * di; acc.w = hv.w * di;

    int s0 = row_ptr[i], s1 = row_ptr[i + 1];
    for (int e = s0; e < s1; ++e) {
        int s = csr_src[e];
        float ds = dinv[s];
        float4 v = h[(size_t)s * dout4 + f];
        acc.x += v.x * ds; acc.y += v.y * ds; acc.z += v.z * ds; acc.w += v.w * ds;
    }
    const float4* b4 = (const float4*)bias;
    float4 b = b4[f];
    float4 o;
    o.x = fmaxf(acc.x * di + b.x, 0.f);
    o.y = fmaxf(acc.y * di + b.y, 0.f);
    o.z = fmaxf(acc.z * di + b.z, 0.f);
    o.w = fmaxf(acc.w * di + b.w, 0.f);

    short2 p0 = split2(o.x), p1 = split2(o.y), p2 = split2(o.z), p3 = split2(o.w);
    size_t base = ((size_t)i << f_shift << 2) + f * 4;
    *(ushort4*)(oh + base) = make_ushort4((unsigned short)p0.x, (unsigned short)p1.x,
                                          (unsigned short)p2.x, (unsigned short)p3.x);
    *(ushort4*)(ol + base) = make_ushort4((unsigned short)p0.y, (unsigned short)p1.y,
                                          (unsigned short)p2.y, (unsigned short)p3.y);
}

// ---------------- aggregation (+bias), fp32 out (layer 4) ----------------

__global__ void k_agg(const float4* __restrict__ h, const int* __restrict__ row_ptr,
                      const int* __restrict__ csr_src, const float* __restrict__ dinv,
                      const float* __restrict__ bias, float4* __restrict__ out,
                      int n, int f_shift) {
    int idx = blockIdx.x * blockDim.x + threadIdx.x;
    int dout4 = 1 << f_shift;
    int total = n << f_shift;
    if (idx >= total) return;
    int i = idx >> f_shift;
    int f = idx & (dout4 - 1);

    float di = dinv[i];
    float4 hv = h[(size_t)i * dout4 + f];
    float4 acc;
    acc.x = hv.x * di; acc.y = hv.y * di; acc.z = hv.z * di; acc.w = hv.w * di;

    int s0 = row_ptr[i], s1 = row_ptr[i + 1];
    for (int e = s0; e < s1; ++e) {
        int s = csr_src[e];
        float ds = dinv[s];
        float4 v = h[(size_t)s * dout4 + f];
        acc.x += v.x * ds; acc.y += v.y * ds; acc.z += v.z * ds; acc.w += v.w * ds;
    }
    const float4* b4 = (const float4*)bias;
    float4 b = b4[f];
    float4 o;
    o.x = acc.x * di + b.x;
    o.y = acc.y * di + b.y;
    o.z = acc.z * di + b.z;
    o.w = acc.w * di + b.w;
    out[(size_t)i * dout4 + f] = o;
}

// ---------------- mean pool per graph (batch sorted) ----------------

__global__ void k_pool(const float* __restrict__ h, const int* __restrict__ batch,
                       int n, float* __restrict__ pooled) {
    int g = blockIdx.x;
    int start, end;
    {
        int lo = 0, hi = n;
        while (lo < hi) { int mid = (lo + hi) >> 1; if (batch[mid] < g) lo = mid + 1; else hi = mid; }
        start = lo;
        lo = start; hi = n;
        while (lo < hi) { int mid = (lo + hi) >> 1; if (batch[mid] < g + 1) lo = mid + 1; else hi = mid; }
        end = lo;
    }
    int f = threadIdx.x & 31;
    int sub = threadIdx.x >> 5;
    float s = 0.f;
    for (int i = start + sub; i < end; i += 8) s += h[(size_t)i * 32 + f];
    __shared__ float red[8][32];
    red[sub][f] = s;
    __syncthreads();
    if (sub == 0) {
        float t = 0.f;
#pragma unroll
        for (int k = 0; k < 8; ++k) t += red[k][f];
        int c = end - start;
        pooled[g * 32 + f] = t / (float)(c > 0 ? c : 1);
    }
}

// ---------------- tiny MLP head ----------------

__global__ void k_mlp(const float* __restrict__ pooled, const float* __restrict__ lw1,
                      const float* __restrict__ lb1, const float* __restrict__ lw2,
                      const float* __restrict__ lb2, float* __restrict__ out, int g_count) {
    int g = threadIdx.x;
    if (g >= g_count) return;
    float p[32];
#pragma unroll
    for (int k = 0; k < 32; ++k) p[k] = pooled[g * 32 + k];
    float hmid[16];
#pragma unroll
    for (int j = 0; j < 16; ++j) {
        float s = lb1[j];
#pragma unroll
        for (int k = 0; k < 32; ++k) s += p[k] * lw1[k * 16 + j];
        hmid[j] = fmaxf(s, 0.f);
    }
#pragma unroll
    for (int o = 0; o < 2; ++o) {
        float s = lb2[o];
#pragma unroll
        for (int k = 0; k < 16; ++k) s += hmid[k] * lw2[k * 2 + o];
        out[g * 2 + o] = s;
    }
}

// ---------------- launch ----------------

extern "C" void kernel_launch(void* const* d_in, const int* in_sizes, int n_in,
                              void* d_out, int out_size, void* d_ws, size_t ws_size,
                              hipStream_t stream) {
    const float* x     = (const float*)d_in[0];
    const int*   ei    = (const int*)d_in[1];
    const int*   batch = (const int*)d_in[2];
    const float* w1 = (const float*)d_in[3];  const float* b1 = (const float*)d_in[4];
    const float* w2 = (const float*)d_in[5];  const float* b2 = (const float*)d_in[6];
    const float* w3 = (const float*)d_in[7];  const float* b3 = (const float*)d_in[8];
    const float* w4 = (const float*)d_in[9];  const float* b4 = (const float*)d_in[10];
    const float* lw1 = (const float*)d_in[11]; const float* lb1 = (const float*)d_in[12];
    const float* lw2 = (const float*)d_in[13]; const float* lb2 = (const float*)d_in[14];
    float* out = (float*)d_out;

    const int n = in_sizes[0] / 512;   // 100000
    const int E = in_sizes[1] / 2;     // 320000
    const int G = 64;

    const int* src = ei;
    const int* dst = ei + E;

    char* ws = (char*)d_ws;
    size_t off = 0;
    auto alloc = [&](size_t bytes) -> void* {
        void* p = ws + off;
        off = (off + bytes + 255) & ~((size_t)255);
        return p;
    };
    float*          bufA = (float*)alloc((size_t)n * 256 * sizeof(float));  // GEMM out
    unsigned short* pAh  = (unsigned short*)alloc((size_t)n * 256 * 2);     // layer planes
    unsigned short* pAl  = (unsigned short*)alloc((size_t)n * 256 * 2);
    int*   cnt     = (int*)alloc((size_t)n * sizeof(int));
    int*   row_ptr = (int*)alloc((size_t)(n + 1) * sizeof(int));
    int*   cursor  = (int*)alloc((size_t)n * sizeof(int));
    int*   csr     = (int*)alloc((size_t)E * sizeof(int));
    float* dinv    = (float*)alloc((size_t)n * sizeof(float));
    float* pooled  = (float*)alloc((size_t)G * 32 * sizeof(float));
    int*   bsum    = (int*)alloc(64 * sizeof(int));
    int*   boff    = (int*)alloc(64 * sizeof(int));
    unsigned short* w1h = (unsigned short*)alloc(256 * 512 * 2);
    unsigned short* w1l = (unsigned short*)alloc(256 * 512 * 2);
    unsigned short* w2h = (unsigned short*)alloc(128 * 256 * 2);
    unsigned short* w2l = (unsigned short*)alloc(128 * 256 * 2);
    unsigned short* w3h = (unsigned short*)alloc(64 * 128 * 2);
    unsigned short* w3l = (unsigned short*)alloc(64 * 128 * 2);
    unsigned short* w4h = (unsigned short*)alloc(32 * 64 * 2);
    unsigned short* w4l = (unsigned short*)alloc(32 * 64 * 2);
    // layer-4 fp32 agg output parked in pAl beyond the live d=64 plane region
    float* bufB = (float*)(pAl + (size_t)n * 64);
    (void)ws_size;

    hipMemsetAsync(cnt, 0, (size_t)n * sizeof(int), stream);
    hipMemsetAsync(cursor, 0, (size_t)n * sizeof(int), stream);

    // weight pre-split (tiny)
    k_split_w<<<(256 * 512 + 255) / 256, 256, 0, stream>>>(w1, 256, 256 * 512, 9, w1h, w1l);
    k_split_w<<<(128 * 256 + 255) / 256, 256, 0, stream>>>(w2, 128, 128 * 256, 8, w2h, w2l);
    k_split_w<<<(64 * 128 + 255) / 256, 256, 0, stream>>>(w3, 64, 64 * 128, 7, w3h, w3l);
    k_split_w<<<(32 * 64 + 255) / 256, 256, 0, stream>>>(w4, 32, 32 * 64, 6, w4h, w4l);

    const int nscan = (n + 4095) / 4096;
    k_count<<<(E + 255) / 256, 256, 0, stream>>>(dst, E, cnt);
    k_dinv <<<(n + 255) / 256, 256, 0, stream>>>(cnt, n, dinv);
    k_scan_sums   <<<nscan, 256, 0, stream>>>(cnt, n, bsum);
    k_scan_offsets<<<1, 64, 0, stream>>>(bsum, nscan, boff, row_ptr + n);
    k_scan_final  <<<nscan, 256, 0, stream>>>(cnt, n, boff, row_ptr);
    k_fill<<<(E + 255) / 256, 256, 0, stream>>>(src, dst, E, row_ptr, cursor, csr);

    const int gy = (n + 127) / 128;   // 782, BM=128

    // layer 1: [n,512]@[512,256], BN=128, single-buffer kernel, x split in-kernel
    k_gemm1<<<dim3(2, gy), 256, 0, stream>>>(x, w1h, w1l, bufA, n);
    k_agg_split<<<((size_t)n * 64 + 255) / 256, 256, 0, stream>>>(
        (const float4*)bufA, row_ptr, csr, dinv, b1, pAh, pAl, n, 6);

    // layer 2: [n,256]@[256,128]
    k_gemm<4><<<dim3(1, gy), 256, 0, stream>>>(pAh, pAl, w2h, w2l, bufA, n, 256, 128);
    k_agg_split<<<((size_t)n * 32 + 255) / 256, 256, 0, stream>>>(
        (const float4*)bufA, row_ptr, csr, dinv, b2, pAh, pAl, n, 5);

    // layer 3: [n,128]@[128,64]
    k_gemm<2><<<dim3(1, gy), 256, 0, stream>>>(pAh, pAl, w3h, w3l, bufA, n, 128, 64);
    k_agg_split<<<((size_t)n * 16 + 255) / 256, 256, 0, stream>>>(
        (const float4*)bufA, row_ptr, csr, dinv, b3, pAh, pAl, n, 4);

    // layer 4: [n,64]@[64,32] (no relu)
    k_gemm<1><<<dim3(1, gy), 256, 0, stream>>>(pAh, pAl, w4h, w4l, bufA, n, 64, 32);
    k_agg<<<((size_t)n * 8 + 255) / 256, 256, 0, stream>>>(
        (const float4*)bufA, row_ptr, csr, dinv, b4, (float4*)bufB, n, 3);

    k_pool<<<G, 256, 0, stream>>>(bufB, batch, n, pooled);
    k_mlp<<<1, 64, 0, stream>>>(pooled, lw1, lb1, lw2, lb2, out, G);
}

// Round 12
// 497.776 us; speedup vs baseline: 1.0293x; 1.0141x over previous
//
#include <hip/hip_runtime.h>
#include <cstdint>
#include <cstddef>

// GCN: 4x GCNConv (512->256->128->64->32) + mean-pool + 2-layer MLP.
// Round 12: r11 with the memset bug fixed (n*4 is NOT a 256B multiple —
// cursor's tail kept poison -> OOB in k_fill). Two separate memsets again.
// GEMM1 keeps the X-2-ahead dbuf schedule; layers 2-4 keep the r8 kernel.

typedef __attribute__((ext_vector_type(8))) short s16x8;
typedef __attribute__((ext_vector_type(4))) float f32x4;

// fp32 -> (bf16 hi, bf16 lo) by truncation; lo captures the truncation error.
__device__ __forceinline__ short2 split2(float f) {
    union { float f; unsigned u; } c; c.f = f;
    short hi = (short)(c.u >> 16);
    union { unsigned u; float f; } h; h.u = c.u & 0xffff0000u;
    union { float f; unsigned u; } r; r.f = f - h.f;
    short lo = (short)(r.u >> 16);
    return make_short2(hi, lo);
}

// async 16B global -> LDS (wave-uniform LDS base; HW adds lane*16)
__device__ __forceinline__ void gload16(const void* g, void* l) {
    __builtin_amdgcn_global_load_lds(
        (const __attribute__((address_space(1))) unsigned int*)g,
        (__attribute__((address_space(3))) unsigned int*)l, 16, 0, 0);
}

// ---------------- CSR build ----------------

__global__ void k_count(const int* __restrict__ dst, int E, int* __restrict__ cnt) {
    int e = blockIdx.x * blockDim.x + threadIdx.x;
    if (e < E) atomicAdd(&cnt[dst[e]], 1);
}

__global__ void k_dinv(const int* __restrict__ cnt, int n, float* __restrict__ dinv) {
    int i = blockIdx.x * blockDim.x + threadIdx.x;
    if (i < n) dinv[i] = rsqrtf((float)(cnt[i] + 1));
}

__global__ void k_scan_sums(const int* __restrict__ cnt, int n, int* __restrict__ bsum) {
    __shared__ int s[256];
    int t = threadIdx.x;
    int base = blockIdx.x * 4096 + t * 16;
    int sum = 0;
#pragma unroll
    for (int j = 0; j < 16; ++j) { int i = base + j; if (i < n) sum += cnt[i]; }
    s[t] = sum;
    __syncthreads();
    for (int off = 128; off > 0; off >>= 1) {
        if (t < off) s[t] += s[t + off];
        __syncthreads();
    }
    if (t == 0) bsum[blockIdx.x] = s[0];
}

__global__ void k_scan_offsets(const int* __restrict__ bsum, int nb,
                               int* __restrict__ boff, int* __restrict__ totalp) {
    int t = threadIdx.x;   // 64 threads
    int v = (t < nb) ? bsum[t] : 0;
    int x = v;
    for (int off = 1; off < 64; off <<= 1) {
        int y = __shfl_up(x, off);
        if (t >= off) x += y;
    }
    if (t < nb) boff[t] = x - v;
    if (t == 63) *totalp = x;
}

__global__ void k_scan_final(const int* __restrict__ cnt, int n,
                             const int* __restrict__ boff, int* __restrict__ row_ptr) {
    __shared__ int s[256];
    int t = threadIdx.x;
    int base = blockIdx.x * 4096 + t * 16;
    int v[16]; int sum = 0;
#pragma unroll
    for (int j = 0; j < 16; ++j) { int i = base + j; v[j] = (i < n) ? cnt[i] : 0; sum += v[j]; }
    s[t] = sum;
    __syncthreads();
    for (int off = 1; off < 256; off <<= 1) {
        int y = (t >= off) ? s[t - off] : 0;
        __syncthreads();
        s[t] += y;
        __syncthreads();
    }
    int run = boff[blockIdx.x] + ((t == 0) ? 0 : s[t - 1]);
#pragma unroll
    for (int j = 0; j < 16; ++j) {
        int i = base + j;
        if (i < n) row_ptr[i] = run;
        run += v[j];
    }
}

__global__ void k_fill(const int* __restrict__ src, const int* __restrict__ dst, int E,
                       const int* __restrict__ row_ptr, int* __restrict__ cursor,
                       int* __restrict__ csr_src) {
    int e = blockIdx.x * blockDim.x + threadIdx.x;
    if (e >= E) return;
    int d = dst[e];
    int p = atomicAdd(&cursor[d], 1);
    csr_src[row_ptr[d] + p] = src[e];
}

// ------- fused weight pre-split: all 4 layers in one launch -------

__global__ void k_split_w_all(const float* __restrict__ w1, const float* __restrict__ w2,
                              const float* __restrict__ w3, const float* __restrict__ w4,
                              unsigned short* __restrict__ w1h, unsigned short* __restrict__ w1l,
                              unsigned short* __restrict__ w2h, unsigned short* __restrict__ w2l,
                              unsigned short* __restrict__ w3h, unsigned short* __restrict__ w3l,
                              unsigned short* __restrict__ w4h, unsigned short* __restrict__ w4l) {
    int idx = blockIdx.x * blockDim.x + threadIdx.x;
    const float* w; unsigned short *th, *tl; int N, ks, loc;
    if (idx < 131072)      { w = w1; th = w1h; tl = w1l; N = 256; ks = 9; loc = idx; }
    else if (idx < 163840) { w = w2; th = w2h; tl = w2l; N = 128; ks = 8; loc = idx - 131072; }
    else if (idx < 172032) { w = w3; th = w3h; tl = w3l; N = 64;  ks = 7; loc = idx - 163840; }
    else if (idx < 174080) { w = w4; th = w4h; tl = w4l; N = 32;  ks = 6; loc = idx - 172032; }
    else return;
    int nn = loc >> ks;
    int k  = loc & ((1 << ks) - 1);
    short2 p = split2(w[(size_t)k * N + nn]);
    th[loc] = (unsigned short)p.x;
    tl[loc] = (unsigned short)p.y;
}

// ---------------- layer-1 GEMM: dbuf + X 2-steps-ahead ----------------
// C[M,256] = x[M,512] @ W1. 256 thr / 4 waves (2x2), BM=BN=128, BK=32.
// Per iter t: X(t+2)->regs, SB(t+1)->LDS gloads, MFMA(t), WA(t+1)
// (split+ds_write; operand X(t+1) was drained by the previous barrier ->
// no stall at WA), __syncthreads. LDS 64KB dbuf.

__global__ __launch_bounds__(256)
void k_gemm1(const float* __restrict__ A32,
             const unsigned short* __restrict__ Bth, const unsigned short* __restrict__ Btl,
             float* __restrict__ C, int M) {
    constexpr int K = 512, KT = 16;
    constexpr int APL = 128 * 64;   // 8KB per A plane
    constexpr int BPL = 128 * 64;
    __shared__ char sA[2][2 * APL];  // [buf][hi|lo]
    __shared__ char sB[2][2 * BPL];

    const int tid  = threadIdx.x;
    const int lane = tid & 63;
    const int w    = tid >> 6;
    const int wm   = w & 1;
    const int wn   = w >> 1;
    const int brow = blockIdx.y * 128;
    const int bcol = blockIdx.x * 128;
    const int l15  = lane & 15;
    const int kb   = (lane >> 4) * 16;

    const int arow  = tid >> 1;
    const int ahalf = tid & 1;
    int ag = brow + arow; if (ag > M - 1) ag = M - 1;   // clamp: dup rows only feed C rows >= M
    const float* xrow = A32 + (size_t)ag * K + ahalf * 16;
    const int vq = (arow >> 1) & 3;
    const int q0 = ((2 * ahalf) ^ vq) * 16;
    const int q1 = ((2 * ahalf + 1) ^ vq) * 16;

    f32x4 acc[4][4];
#pragma unroll
    for (int i = 0; i < 4; ++i)
#pragma unroll
        for (int j = 0; j < 4; ++j) acc[i][j] = (f32x4){0.f, 0.f, 0.f, 0.f};

    float4 xr[2][4];   // ping-pong X reg sets; loop fully unrolled -> static idx

    auto X = [&](int t, int p) {
        const float4* q = (const float4*)(xrow + t * 32);
        xr[p][0] = q[0]; xr[p][1] = q[1]; xr[p][2] = q[2]; xr[p][3] = q[3];
    };
    auto WA = [&](char* abuf, int p) {
        float v[16] = {xr[p][0].x, xr[p][0].y, xr[p][0].z, xr[p][0].w,
                       xr[p][1].x, xr[p][1].y, xr[p][1].z, xr[p][1].w,
                       xr[p][2].x, xr[p][2].y, xr[p][2].z, xr[p][2].w,
                       xr[p][3].x, xr[p][3].y, xr[p][3].z, xr[p][3].w};
        s16x8 h0, h1, l0, l1;
#pragma unroll
        for (int j = 0; j < 8; ++j) { short2 q = split2(v[j]);     h0[j] = q.x; l0[j] = q.y; }
#pragma unroll
        for (int j = 0; j < 8; ++j) { short2 q = split2(v[8 + j]); h1[j] = q.x; l1[j] = q.y; }
        *(s16x8*)(abuf + arow * 64 + q0)       = h0;
        *(s16x8*)(abuf + arow * 64 + q1)       = h1;
        *(s16x8*)(abuf + APL + arow * 64 + q0) = l0;
        *(s16x8*)(abuf + APL + arow * 64 + q1) = l1;
    };
    auto SB = [&](char* bbuf, int t) {
#pragma unroll
        for (int u = 0; u < 4; ++u) {
            int id = w + u * 4;                 // 0..15
            int hi = (id < 8) ? 1 : 0;
            int s  = hi ? id : id - 8;
            int p  = s * 64 + lane;
            int kq = (p ^ ((p >> 3) & 3)) & 3;
            int col = p >> 2;
            const unsigned short* gs = (hi ? Bth : Btl) + (size_t)(bcol + col) * K + t * 32 + kq * 8;
            gload16(gs, (hi ? bbuf : bbuf + BPL) + s * 1024);
        }
    };
    auto MM = [&](char* abuf, char* bbuf) {
        char* sAl = abuf + APL;
        char* sBl = bbuf + BPL;
        s16x8 fah[4], fam[4];
#pragma unroll
        for (int i = 0; i < 4; ++i) {
            int row = wm * 64 + i * 16 + l15;
            int o = row * 64 + (kb ^ (((row >> 1) & 3) << 4));
            fah[i] = *(const s16x8*)(abuf + o);
            fam[i] = *(const s16x8*)(sAl + o);
        }
#pragma unroll
        for (int j = 0; j < 4; ++j) {
            int col = wn * 64 + j * 16 + l15;
            int o = col * 64 + (kb ^ (((col >> 1) & 3) << 4));
            s16x8 fbh = *(const s16x8*)(bbuf + o);
            s16x8 fbm = *(const s16x8*)(sBl + o);
#pragma unroll
            for (int i = 0; i < 4; ++i) {
                acc[i][j] = __builtin_amdgcn_mfma_f32_16x16x32_bf16(fah[i], fbh, acc[i][j], 0, 0, 0);
                acc[i][j] = __builtin_amdgcn_mfma_f32_16x16x32_bf16(fam[i], fbh, acc[i][j], 0, 0, 0);
                acc[i][j] = __builtin_amdgcn_mfma_f32_16x16x32_bf16(fah[i], fbm, acc[i][j], 0, 0, 0);
            }
        }
    };

    // prologue: X(0),X(1) in flight; stage tile 0 (B gloads + A write)
    X(0, 0);
    X(1, 1);
    SB(sB[0], 0);
    WA(sA[0], 0);        // waits X(0) (counted, compiler)
    __syncthreads();     // drains SB(0), X(1)

#pragma unroll
    for (int t = 0; t < KT; ++t) {
        if (t + 2 < KT) X(t + 2, t & 1);          // refill the set consumed last iter
        if (t + 1 < KT) SB(sB[(t + 1) & 1], t + 1);
        MM(sA[t & 1], sB[t & 1]);
        if (t + 1 < KT) WA(sA[(t + 1) & 1], (t + 1) & 1);   // X(t+1) already drained
        __syncthreads();
    }

    // C/D layout: col = lane&15, row = (lane>>4)*4 + reg
#pragma unroll
    for (int i = 0; i < 4; ++i) {
#pragma unroll
        for (int r = 0; r < 4; ++r) {
            int row = brow + wm * 64 + i * 16 + (lane >> 4) * 4 + r;
            if (row >= M) continue;
#pragma unroll
            for (int j = 0; j < 4; ++j) {
                int col = bcol + wn * 64 + j * 16 + l15;
                C[(size_t)row * 256 + col] = acc[i][j][r];
            }
        }
    }
}

// ---------------- 2-phase dbuf split-bf16 MFMA GEMM (layers 2-4) ----------------

template <int FN>
__global__ __launch_bounds__(256)
void k_gemm(const unsigned short* __restrict__ Ah, const unsigned short* __restrict__ Al,
            const unsigned short* __restrict__ Bth, const unsigned short* __restrict__ Btl,
            float* __restrict__ C, int M, int K, int N) {
    constexpr int FM = 4;
    constexpr int BM = 128;
    constexpr int BN = FN * 32;
    constexpr int ABYTES = BM * 64;
    constexpr int BBYTES = BN * 64;
    constexpr int BUF = 2 * ABYTES + 2 * BBYTES;
    __shared__ char lds[2 * BUF];

    const int tid  = threadIdx.x;
    const int lane = tid & 63;
    const int w    = tid >> 6;
    const int wm   = w & 1;
    const int wn   = w >> 1;
    const int brow = blockIdx.y * BM;
    const int bcol = blockIdx.x * BN;
    const int l15  = lane & 15;
    const int kb   = (lane >> 4) * 16;

    f32x4 acc[FM][FN];
#pragma unroll
    for (int i = 0; i < FM; ++i)
#pragma unroll
        for (int j = 0; j < FN; ++j) acc[i][j] = (f32x4){0.f, 0.f, 0.f, 0.f};

    auto stageA = [&](char* base, int k0) {
#pragma unroll
        for (int u = 0; u < 4; ++u) {
            int id = w + u * 4;
            int hi = (id < 8) ? 1 : 0;
            int s  = hi ? id : id - 8;
            int p  = s * 64 + lane;
            int kq = (p ^ ((p >> 3) & 3)) & 3;
            int row = p >> 2;
            const unsigned short* gs = (hi ? Ah : Al) + (size_t)(brow + row) * K + k0 + kq * 8;
            gload16(gs, base + (hi ? 0 : ABYTES) + s * 1024);
        }
    };
    auto stageB = [&](char* base, int k0) {
        char* sBh = base + 2 * ABYTES;
        char* sBl = sBh + BBYTES;
#pragma unroll
        for (int u = 0; u < BN / 32; ++u) {
            int id = w + u * 4;
            int hi = (id < BN / 16) ? 1 : 0;
            int s  = hi ? id : id - BN / 16;
            int p  = s * 64 + lane;
            int kq = (p ^ ((p >> 3) & 3)) & 3;
            int col = p >> 2;
            const unsigned short* gs = (hi ? Bth : Btl) + (size_t)(bcol + col) * K + k0 + kq * 8;
            gload16(gs, (hi ? sBh : sBl) + s * 1024);
        }
    };

    char* cur = lds;
    char* nxt = lds + BUF;
    stageB(cur, 0);
    stageA(cur, 0);
    __syncthreads();

    const int KT = K / 32;
    for (int t = 0; t < KT; ++t) {
        const int k1 = (t + 1) * 32;
        if (t + 1 < KT) {
            stageB(nxt, k1);
            stageA(nxt, k1);
        }
        {
            char* sAh = cur;
            char* sAl = cur + ABYTES;
            char* sBh = cur + 2 * ABYTES;
            char* sBl = sBh + BBYTES;
            s16x8 fah[FM], fam[FM];
#pragma unroll
            for (int i = 0; i < FM; ++i) {
                int row = wm * 64 + i * 16 + l15;
                int o = row * 64 + (kb ^ (((row >> 1) & 3) << 4));
                fah[i] = *(const s16x8*)(sAh + o);
                fam[i] = *(const s16x8*)(sAl + o);
            }
#pragma unroll
            for (int j = 0; j < FN; ++j) {
                int col = wn * FN * 16 + j * 16 + l15;
                int o = col * 64 + (kb ^ (((col >> 1) & 3) << 4));
                s16x8 fbh = *(const s16x8*)(sBh + o);
                s16x8 fbm = *(const s16x8*)(sBl + o);
#pragma unroll
                for (int i = 0; i < FM; ++i) {
                    acc[i][j] = __builtin_amdgcn_mfma_f32_16x16x32_bf16(fah[i], fbh, acc[i][j], 0, 0, 0);
                    acc[i][j] = __builtin_amdgcn_mfma_f32_16x16x32_bf16(fam[i], fbh, acc[i][j], 0, 0, 0);
                    acc[i][j] = __builtin_amdgcn_mfma_f32_16x16x32_bf16(fah[i], fbm, acc[i][j], 0, 0, 0);
                }
            }
        }
        __syncthreads();
        char* tmp = cur; cur = nxt; nxt = tmp;
    }

#pragma unroll
    for (int i = 0; i < FM; ++i) {
#pragma unroll
        for (int r = 0; r < 4; ++r) {
            int row = brow + wm * 64 + i * 16 + (lane >> 4) * 4 + r;
            if (row >= M) continue;
#pragma unroll
            for (int j = 0; j < FN; ++j) {
                int col = bcol + wn * FN * 16 + j * 16 + l15;
                C[(size_t)row * N + col] = acc[i][j][r];
            }
        }
    }
}

// ---------------- aggregation (+bias, relu) -> bf16 hi/lo planes ----------------

__global__ void k_agg_split(const float4* __restrict__ h, const int* __restrict__ row_ptr,
                            const int* __restrict__ csr_src, const float* __restrict__ dinv,
                            const float* __restrict__ bias,
                            unsigned short* __restrict__ oh, unsigned short* __restrict__ ol,
                            int n, int f_shift) {
    int idx = blockIdx.x * blockDim.x + threadIdx.x;
    int dout4 = 1 << f_shift;
    int total = n << f_shift;
    if (idx >= total) return;
    int i = idx >> f_shift;
    int f = idx & (dout4 - 1);

    float di = dinv[i];
    float4 hv = h[(size_t)i * dout4 + f];
    float4 acc;
    acc.x = hv.x * di; acc.y = hv.y * di; acc.z = hv.z * di; acc.w = hv.w * di;

    int s0 = row_ptr[i], s1 = row_ptr[i + 1];
    for (int e = s0; e < s1; ++e) {
        int s = csr_src[e];
        float ds = dinv[s];
        float4 v = h[(size_t)s * dout4 + f];
        acc.x += v.x * ds; acc.y += v.y * ds; acc.z += v.z * ds; acc.w += v.w * ds;
    }
    const float4* b4 = (const float4*)bias;
    float4 b = b4[f];
    float4 o;
    o.x = fmaxf(acc.x * di + b.x, 0.f);
    o.y = fmaxf(acc.y * di + b.y, 0.f);
    o.z = fmaxf(acc.z * di + b.z, 0.f);
    o.w = fmaxf(acc.w * di + b.w, 0.f);

    short2 p0 = split2(o.x), p1 = split2(o.y), p2 = split2(o.z), p3 = split2(o.w);
    size_t base = ((size_t)i << f_shift << 2) + f * 4;
    *(ushort4*)(oh + base) = make_ushort4((unsigned short)p0.x, (unsigned short)p1.x,
                                          (unsigned short)p2.x, (unsigned short)p3.x);
    *(ushort4*)(ol + base) = make_ushort4((unsigned short)p0.y, (unsigned short)p1.y,
                                          (unsigned short)p2.y, (unsigned short)p3.y);
}

// ---------------- aggregation (+bias), fp32 out (layer 4) ----------------

__global__ void k_agg(const float4* __restrict__ h, const int* __restrict__ row_ptr,
                      const int* __restrict__ csr_src, const float* __restrict__ dinv,
                      const float* __restrict__ bias, float4* __restrict__ out,
                      int n, int f_shift) {
    int idx = blockIdx.x * blockDim.x + threadIdx.x;
    int dout4 = 1 << f_shift;
    int total = n << f_shift;
    if (idx >= total) return;
    int i = idx >> f_shift;
    int f = idx & (dout4 - 1);

    float di = dinv[i];
    float4 hv = h[(size_t)i * dout4 + f];
    float4 acc;
    acc.x = hv.x * di; acc.y = hv.y * di; acc.z = hv.z * di; acc.w = hv.w * di;

    int s0 = row_ptr[i], s1 = row_ptr[i + 1];
    for (int e = s0; e < s1; ++e) {
        int s = csr_src[e];
        float ds = dinv[s];
        float4 v = h[(size_t)s * dout4 + f];
        acc.x += v.x * ds; acc.y += v.y * ds; acc.z += v.z * ds; acc.w += v.w * ds;
    }
    const float4* b4 = (const float4*)bias;
    float4 b = b4[f];
    float4 o;
    o.x = acc.x * di + b.x;
    o.y = acc.y * di + b.y;
    o.z = acc.z * di + b.z;
    o.w = acc.w * di + b.w;
    out[(size_t)i * dout4 + f] = o;
}

// ---------------- mean pool per graph (batch sorted) ----------------

__global__ void k_pool(const float* __restrict__ h, const int* __restrict__ batch,
                       int n, float* __restrict__ pooled) {
    int g = blockIdx.x;
    int start, end;
    {
        int lo = 0, hi = n;
        while (lo < hi) { int mid = (lo + hi) >> 1; if (batch[mid] < g) lo = mid + 1; else hi = mid; }
        start = lo;
        lo = start; hi = n;
        while (lo < hi) { int mid = (lo + hi) >> 1; if (batch[mid] < g + 1) lo = mid + 1; else hi = mid; }
        end = lo;
    }
    int f = threadIdx.x & 31;
    int sub = threadIdx.x >> 5;
    float s = 0.f;
    for (int i = start + sub; i < end; i += 8) s += h[(size_t)i * 32 + f];
    __shared__ float red[8][32];
    red[sub][f] = s;
    __syncthreads();
    if (sub == 0) {
        float t = 0.f;
#pragma unroll
        for (int k = 0; k < 8; ++k) t += red[k][f];
        int c = end - start;
        pooled[g * 32 + f] = t / (float)(c > 0 ? c : 1);
    }
}

// ---------------- tiny MLP head ----------------

__global__ void k_mlp(const float* __restrict__ pooled, const float* __restrict__ lw1,
                      const float* __restrict__ lb1, const float* __restrict__ lw2,
                      const float* __restrict__ lb2, float* __restrict__ out, int g_count) {
    int g = threadIdx.x;
    if (g >= g_count) return;
    float p[32];
#pragma unroll
    for (int k = 0; k < 32; ++k) p[k] = pooled[g * 32 + k];
    float hmid[16];
#pragma unroll
    for (int j = 0; j < 16; ++j) {
        float s = lb1[j];
#pragma unroll
        for (int k = 0; k < 32; ++k) s += p[k] * lw1[k * 16 + j];
        hmid[j] = fmaxf(s, 0.f);
    }
#pragma unroll
    for (int o = 0; o < 2; ++o) {
        float s = lb2[o];
#pragma unroll
        for (int k = 0; k < 16; ++k) s += hmid[k] * lw2[k * 2 + o];
        out[g * 2 + o] = s;
    }
}

// ---------------- launch ----------------

extern "C" void kernel_launch(void* const* d_in, const int* in_sizes, int n_in,
                              void* d_out, int out_size, void* d_ws, size_t ws_size,
                              hipStream_t stream) {
    const float* x     = (const float*)d_in[0];
    const int*   ei    = (const int*)d_in[1];
    const int*   batch = (const int*)d_in[2];
    const float* w1 = (const float*)d_in[3];  const float* b1 = (const float*)d_in[4];
    const float* w2 = (const float*)d_in[5];  const float* b2 = (const float*)d_in[6];
    const float* w3 = (const float*)d_in[7];  const float* b3 = (const float*)d_in[8];
    const float* w4 = (const float*)d_in[9];  const float* b4 = (const float*)d_in[10];
    const float* lw1 = (const float*)d_in[11]; const float* lb1 = (const float*)d_in[12];
    const float* lw2 = (const float*)d_in[13]; const float* lb2 = (const float*)d_in[14];
    float* out = (float*)d_out;

    const int n = in_sizes[0] / 512;   // 100000
    const int E = in_sizes[1] / 2;     // 320000
    const int G = 64;

    const int* src = ei;
    const int* dst = ei + E;

    char* ws = (char*)d_ws;
    size_t off = 0;
    auto alloc = [&](size_t bytes) -> void* {
        void* p = ws + off;
        off = (off + bytes + 255) & ~((size_t)255);
        return p;
    };
    float*          bufA = (float*)alloc((size_t)n * 256 * sizeof(float));  // GEMM out
    unsigned short* pAh  = (unsigned short*)alloc((size_t)n * 256 * 2);     // layer planes
    unsigned short* pAl  = (unsigned short*)alloc((size_t)n * 256 * 2);
    int*   cnt     = (int*)alloc((size_t)n * sizeof(int));
    int*   cursor  = (int*)alloc((size_t)n * sizeof(int));
    int*   row_ptr = (int*)alloc((size_t)(n + 1) * sizeof(int));
    int*   csr     = (int*)alloc((size_t)E * sizeof(int));
    float* dinv    = (float*)alloc((size_t)n * sizeof(float));
    float* pooled  = (float*)alloc((size_t)G * 32 * sizeof(float));
    int*   bsum    = (int*)alloc(64 * sizeof(int));
    int*   boff    = (int*)alloc(64 * sizeof(int));
    unsigned short* w1h = (unsigned short*)alloc(256 * 512 * 2);
    unsigned short* w1l = (unsigned short*)alloc(256 * 512 * 2);
    unsigned short* w2h = (unsigned short*)alloc(128 * 256 * 2);
    unsigned short* w2l = (unsigned short*)alloc(128 * 256 * 2);
    unsigned short* w3h = (unsigned short*)alloc(64 * 128 * 2);
    unsigned short* w3l = (unsigned short*)alloc(64 * 128 * 2);
    unsigned short* w4h = (unsigned short*)alloc(32 * 64 * 2);
    unsigned short* w4l = (unsigned short*)alloc(32 * 64 * 2);
    // layer-4 fp32 agg output parked in pAl beyond the live d=64 plane region
    float* bufB = (float*)(pAl + (size_t)n * 64);
    (void)ws_size;

    // NOTE: n*sizeof(int) is NOT a 256B multiple (r11 bug) — zero each separately.
    hipMemsetAsync(cnt, 0, (size_t)n * sizeof(int), stream);
    hipMemsetAsync(cursor, 0, (size_t)n * sizeof(int), stream);

    // fused weight pre-split (1 launch)
    k_split_w_all<<<(174080 + 255) / 256, 256, 0, stream>>>(
        w1, w2, w3, w4, w1h, w1l, w2h, w2l, w3h, w3l, w4h, w4l);

    const int nscan = (n + 4095) / 4096;
    k_count<<<(E + 255) / 256, 256, 0, stream>>>(dst, E, cnt);
    k_dinv <<<(n + 255) / 256, 256, 0, stream>>>(cnt, n, dinv);
    k_scan_sums   <<<nscan, 256, 0, stream>>>(cnt, n, bsum);
    k_scan_offsets<<<1, 64, 0, stream>>>(bsum, nscan, boff, row_ptr + n);
    k_scan_final  <<<nscan, 256, 0, stream>>>(cnt, n, boff, row_ptr);
    k_fill<<<(E + 255) / 256, 256, 0, stream>>>(src, dst, E, row_ptr, cursor, csr);

    const int gy = (n + 127) / 128;   // 782, BM=128

    // layer 1: [n,512]@[512,256], BN=128, dbuf + X-2-ahead, x split in-kernel
    k_gemm1<<<dim3(2, gy), 256, 0, stream>>>(x, w1h, w1l, bufA, n);
    k_agg_split<<<((size_t)n * 64 + 255) / 256, 256, 0, stream>>>(
        (const float4*)bufA, row_ptr, csr, dinv, b1, pAh, pAl, n, 6);

    // layer 2: [n,256]@[256,128]
    k_gemm<4><<<dim3(1, gy), 256, 0, stream>>>(pAh, pAl, w2h, w2l, bufA, n, 256, 128);
    k_agg_split<<<((size_t)n * 32 + 255) / 256, 256, 0, stream>>>(
        (const float4*)bufA, row_ptr, csr, dinv, b2, pAh, pAl, n, 5);

    // layer 3: [n,128]@[128,64]
    k_gemm<2><<<dim3(1, gy), 256, 0, stream>>>(pAh, pAl, w3h, w3l, bufA, n, 128, 64);
    k_agg_split<<<((size_t)n * 16 + 255) / 256, 256, 0, stream>>>(
        (const float4*)bufA, row_ptr, csr, dinv, b3, pAh, pAl, n, 4);

    // layer 4: [n,64]@[64,32] (no relu)
    k_gemm<1><<<dim3(1, gy), 256, 0, stream>>>(pAh, pAl, w4h, w4l, bufA, n, 64, 32);
    k_agg<<<((size_t)n * 8 + 255) / 256, 256, 0, stream>>>(
        (const float4*)bufA, row_ptr, csr, dinv, b4, (float4*)bufB, n, 3);

    k_pool<<<G, 256, 0, stream>>>(bufB, batch, n, pooled);
    k_mlp<<<1, 64, 0, stream>>>(pooled, lw1, lb1, lw2, lb2, out, G);
}

// Round 13
// 485.455 us; speedup vs baseline: 1.0554x; 1.0254x over previous
//
#include <hip/hip_runtime.h>
#include <cstdint>
#include <cstddef>

// GCN: 4x GCNConv (512->256->128->64->32) + mean-pool + 2-layer MLP.
// Round 13: aggregation rework — per-edge norm precomputed in k_fill
// (kills the dependent dinv[s] load), 2-edge-unrolled gather (2 row loads
// in flight). GEMM1 keeps the r12 schedule; layers 2-4 keep the r8 kernel.

typedef __attribute__((ext_vector_type(8))) short s16x8;
typedef __attribute__((ext_vector_type(4))) float f32x4;

// fp32 -> (bf16 hi, bf16 lo) by truncation; lo captures the truncation error.
__device__ __forceinline__ short2 split2(float f) {
    union { float f; unsigned u; } c; c.f = f;
    short hi = (short)(c.u >> 16);
    union { unsigned u; float f; } h; h.u = c.u & 0xffff0000u;
    union { float f; unsigned u; } r; r.f = f - h.f;
    short lo = (short)(r.u >> 16);
    return make_short2(hi, lo);
}

// async 16B global -> LDS (wave-uniform LDS base; HW adds lane*16)
__device__ __forceinline__ void gload16(const void* g, void* l) {
    __builtin_amdgcn_global_load_lds(
        (const __attribute__((address_space(1))) unsigned int*)g,
        (__attribute__((address_space(3))) unsigned int*)l, 16, 0, 0);
}

// ---------------- CSR build ----------------

__global__ void k_count(const int* __restrict__ dst, int E, int* __restrict__ cnt) {
    int e = blockIdx.x * blockDim.x + threadIdx.x;
    if (e < E) atomicAdd(&cnt[dst[e]], 1);
}

__global__ void k_dinv(const int* __restrict__ cnt, int n, float* __restrict__ dinv) {
    int i = blockIdx.x * blockDim.x + threadIdx.x;
    if (i < n) dinv[i] = rsqrtf((float)(cnt[i] + 1));
}

__global__ void k_scan_sums(const int* __restrict__ cnt, int n, int* __restrict__ bsum) {
    __shared__ int s[256];
    int t = threadIdx.x;
    int base = blockIdx.x * 4096 + t * 16;
    int sum = 0;
#pragma unroll
    for (int j = 0; j < 16; ++j) { int i = base + j; if (i < n) sum += cnt[i]; }
    s[t] = sum;
    __syncthreads();
    for (int off = 128; off > 0; off >>= 1) {
        if (t < off) s[t] += s[t + off];
        __syncthreads();
    }
    if (t == 0) bsum[blockIdx.x] = s[0];
}

__global__ void k_scan_offsets(const int* __restrict__ bsum, int nb,
                               int* __restrict__ boff, int* __restrict__ totalp) {
    int t = threadIdx.x;   // 64 threads
    int v = (t < nb) ? bsum[t] : 0;
    int x = v;
    for (int off = 1; off < 64; off <<= 1) {
        int y = __shfl_up(x, off);
        if (t >= off) x += y;
    }
    if (t < nb) boff[t] = x - v;
    if (t == 63) *totalp = x;
}

__global__ void k_scan_final(const int* __restrict__ cnt, int n,
                             const int* __restrict__ boff, int* __restrict__ row_ptr) {
    __shared__ int s[256];
    int t = threadIdx.x;
    int base = blockIdx.x * 4096 + t * 16;
    int v[16]; int sum = 0;
#pragma unroll
    for (int j = 0; j < 16; ++j) { int i = base + j; v[j] = (i < n) ? cnt[i] : 0; sum += v[j]; }
    s[t] = sum;
    __syncthreads();
    for (int off = 1; off < 256; off <<= 1) {
        int y = (t >= off) ? s[t - off] : 0;
        __syncthreads();
        s[t] += y;
        __syncthreads();
    }
    int run = boff[blockIdx.x] + ((t == 0) ? 0 : s[t - 1]);
#pragma unroll
    for (int j = 0; j < 16; ++j) {
        int i = base + j;
        if (i < n) row_ptr[i] = run;
        run += v[j];
    }
}

// fill CSR and the per-edge normalization weight norm = dinv[src]*dinv[dst]
__global__ void k_fill(const int* __restrict__ src, const int* __restrict__ dst, int E,
                       const int* __restrict__ row_ptr, int* __restrict__ cursor,
                       const float* __restrict__ dinv,
                       int* __restrict__ csr_src, float* __restrict__ csr_norm) {
    int e = blockIdx.x * blockDim.x + threadIdx.x;
    if (e >= E) return;
    int d = dst[e];
    int s = src[e];
    int p = atomicAdd(&cursor[d], 1);
    int slot = row_ptr[d] + p;
    csr_src[slot]  = s;
    csr_norm[slot] = dinv[s] * dinv[d];
}

// ------- fused weight pre-split: all 4 layers in one launch -------

__global__ void k_split_w_all(const float* __restrict__ w1, const float* __restrict__ w2,
                              const float* __restrict__ w3, const float* __restrict__ w4,
                              unsigned short* __restrict__ w1h, unsigned short* __restrict__ w1l,
                              unsigned short* __restrict__ w2h, unsigned short* __restrict__ w2l,
                              unsigned short* __restrict__ w3h, unsigned short* __restrict__ w3l,
                              unsigned short* __restrict__ w4h, unsigned short* __restrict__ w4l) {
    int idx = blockIdx.x * blockDim.x + threadIdx.x;
    const float* w; unsigned short *th, *tl; int N, ks, loc;
    if (idx < 131072)      { w = w1; th = w1h; tl = w1l; N = 256; ks = 9; loc = idx; }
    else if (idx < 163840) { w = w2; th = w2h; tl = w2l; N = 128; ks = 8; loc = idx - 131072; }
    else if (idx < 172032) { w = w3; th = w3h; tl = w3l; N = 64;  ks = 7; loc = idx - 163840; }
    else if (idx < 174080) { w = w4; th = w4h; tl = w4l; N = 32;  ks = 6; loc = idx - 172032; }
    else return;
    int nn = loc >> ks;
    int k  = loc & ((1 << ks) - 1);
    short2 p = split2(w[(size_t)k * N + nn]);
    th[loc] = (unsigned short)p.x;
    tl[loc] = (unsigned short)p.y;
}

// ---------------- layer-1 GEMM: dbuf + X 2-steps-ahead (r12) ----------------

__global__ __launch_bounds__(256)
void k_gemm1(const float* __restrict__ A32,
             const unsigned short* __restrict__ Bth, const unsigned short* __restrict__ Btl,
             float* __restrict__ C, int M) {
    constexpr int K = 512, KT = 16;
    constexpr int APL = 128 * 64;   // 8KB per A plane
    constexpr int BPL = 128 * 64;
    __shared__ char sA[2][2 * APL];  // [buf][hi|lo]
    __shared__ char sB[2][2 * BPL];

    const int tid  = threadIdx.x;
    const int lane = tid & 63;
    const int w    = tid >> 6;
    const int wm   = w & 1;
    const int wn   = w >> 1;
    const int brow = blockIdx.y * 128;
    const int bcol = blockIdx.x * 128;
    const int l15  = lane & 15;
    const int kb   = (lane >> 4) * 16;

    const int arow  = tid >> 1;
    const int ahalf = tid & 1;
    int ag = brow + arow; if (ag > M - 1) ag = M - 1;   // clamp: dup rows only feed C rows >= M
    const float* xrow = A32 + (size_t)ag * K + ahalf * 16;
    const int vq = (arow >> 1) & 3;
    const int q0 = ((2 * ahalf) ^ vq) * 16;
    const int q1 = ((2 * ahalf + 1) ^ vq) * 16;

    f32x4 acc[4][4];
#pragma unroll
    for (int i = 0; i < 4; ++i)
#pragma unroll
        for (int j = 0; j < 4; ++j) acc[i][j] = (f32x4){0.f, 0.f, 0.f, 0.f};

    float4 xr[2][4];   // ping-pong X reg sets; loop fully unrolled -> static idx

    auto X = [&](int t, int p) {
        const float4* q = (const float4*)(xrow + t * 32);
        xr[p][0] = q[0]; xr[p][1] = q[1]; xr[p][2] = q[2]; xr[p][3] = q[3];
    };
    auto WA = [&](char* abuf, int p) {
        float v[16] = {xr[p][0].x, xr[p][0].y, xr[p][0].z, xr[p][0].w,
                       xr[p][1].x, xr[p][1].y, xr[p][1].z, xr[p][1].w,
                       xr[p][2].x, xr[p][2].y, xr[p][2].z, xr[p][2].w,
                       xr[p][3].x, xr[p][3].y, xr[p][3].z, xr[p][3].w};
        s16x8 h0, h1, l0, l1;
#pragma unroll
        for (int j = 0; j < 8; ++j) { short2 q = split2(v[j]);     h0[j] = q.x; l0[j] = q.y; }
#pragma unroll
        for (int j = 0; j < 8; ++j) { short2 q = split2(v[8 + j]); h1[j] = q.x; l1[j] = q.y; }
        *(s16x8*)(abuf + arow * 64 + q0)       = h0;
        *(s16x8*)(abuf + arow * 64 + q1)       = h1;
        *(s16x8*)(abuf + APL + arow * 64 + q0) = l0;
        *(s16x8*)(abuf + APL + arow * 64 + q1) = l1;
    };
    auto SB = [&](char* bbuf, int t) {
#pragma unroll
        for (int u = 0; u < 4; ++u) {
            int id = w + u * 4;                 // 0..15
            int hi = (id < 8) ? 1 : 0;
            int s  = hi ? id : id - 8;
            int p  = s * 64 + lane;
            int kq = (p ^ ((p >> 3) & 3)) & 3;
            int col = p >> 2;
            const unsigned short* gs = (hi ? Bth : Btl) + (size_t)(bcol + col) * K + t * 32 + kq * 8;
            gload16(gs, (hi ? bbuf : bbuf + BPL) + s * 1024);
        }
    };
    auto MM = [&](char* abuf, char* bbuf) {
        char* sAl = abuf + APL;
        char* sBl = bbuf + BPL;
        s16x8 fah[4], fam[4];
#pragma unroll
        for (int i = 0; i < 4; ++i) {
            int row = wm * 64 + i * 16 + l15;
            int o = row * 64 + (kb ^ (((row >> 1) & 3) << 4));
            fah[i] = *(const s16x8*)(abuf + o);
            fam[i] = *(const s16x8*)(sAl + o);
        }
#pragma unroll
        for (int j = 0; j < 4; ++j) {
            int col = wn * 64 + j * 16 + l15;
            int o = col * 64 + (kb ^ (((col >> 1) & 3) << 4));
            s16x8 fbh = *(const s16x8*)(bbuf + o);
            s16x8 fbm = *(const s16x8*)(sBl + o);
#pragma unroll
            for (int i = 0; i < 4; ++i) {
                acc[i][j] = __builtin_amdgcn_mfma_f32_16x16x32_bf16(fah[i], fbh, acc[i][j], 0, 0, 0);
                acc[i][j] = __builtin_amdgcn_mfma_f32_16x16x32_bf16(fam[i], fbh, acc[i][j], 0, 0, 0);
                acc[i][j] = __builtin_amdgcn_mfma_f32_16x16x32_bf16(fah[i], fbm, acc[i][j], 0, 0, 0);
            }
        }
    };

    // prologue
    X(0, 0);
    X(1, 1);
    SB(sB[0], 0);
    WA(sA[0], 0);
    __syncthreads();

#pragma unroll
    for (int t = 0; t < KT; ++t) {
        if (t + 2 < KT) X(t + 2, t & 1);
        if (t + 1 < KT) SB(sB[(t + 1) & 1], t + 1);
        MM(sA[t & 1], sB[t & 1]);
        if (t + 1 < KT) WA(sA[(t + 1) & 1], (t + 1) & 1);
        __syncthreads();
    }

    // C/D layout: col = lane&15, row = (lane>>4)*4 + reg
#pragma unroll
    for (int i = 0; i < 4; ++i) {
#pragma unroll
        for (int r = 0; r < 4; ++r) {
            int row = brow + wm * 64 + i * 16 + (lane >> 4) * 4 + r;
            if (row >= M) continue;
#pragma unroll
            for (int j = 0; j < 4; ++j) {
                int col = bcol + wn * 64 + j * 16 + l15;
                C[(size_t)row * 256 + col] = acc[i][j][r];
            }
        }
    }
}

// ---------------- 2-phase dbuf split-bf16 MFMA GEMM (layers 2-4) ----------------

template <int FN>
__global__ __launch_bounds__(256)
void k_gemm(const unsigned short* __restrict__ Ah, const unsigned short* __restrict__ Al,
            const unsigned short* __restrict__ Bth, const unsigned short* __restrict__ Btl,
            float* __restrict__ C, int M, int K, int N) {
    constexpr int FM = 4;
    constexpr int BM = 128;
    constexpr int BN = FN * 32;
    constexpr int ABYTES = BM * 64;
    constexpr int BBYTES = BN * 64;
    constexpr int BUF = 2 * ABYTES + 2 * BBYTES;
    __shared__ char lds[2 * BUF];

    const int tid  = threadIdx.x;
    const int lane = tid & 63;
    const int w    = tid >> 6;
    const int wm   = w & 1;
    const int wn   = w >> 1;
    const int brow = blockIdx.y * BM;
    const int bcol = blockIdx.x * BN;
    const int l15  = lane & 15;
    const int kb   = (lane >> 4) * 16;

    f32x4 acc[FM][FN];
#pragma unroll
    for (int i = 0; i < FM; ++i)
#pragma unroll
        for (int j = 0; j < FN; ++j) acc[i][j] = (f32x4){0.f, 0.f, 0.f, 0.f};

    auto stageA = [&](char* base, int k0) {
#pragma unroll
        for (int u = 0; u < 4; ++u) {
            int id = w + u * 4;
            int hi = (id < 8) ? 1 : 0;
            int s  = hi ? id : id - 8;
            int p  = s * 64 + lane;
            int kq = (p ^ ((p >> 3) & 3)) & 3;
            int row = p >> 2;
            const unsigned short* gs = (hi ? Ah : Al) + (size_t)(brow + row) * K + k0 + kq * 8;
            gload16(gs, base + (hi ? 0 : ABYTES) + s * 1024);
        }
    };
    auto stageB = [&](char* base, int k0) {
        char* sBh = base + 2 * ABYTES;
        char* sBl = sBh + BBYTES;
#pragma unroll
        for (int u = 0; u < BN / 32; ++u) {
            int id = w + u * 4;
            int hi = (id < BN / 16) ? 1 : 0;
            int s  = hi ? id : id - BN / 16;
            int p  = s * 64 + lane;
            int kq = (p ^ ((p >> 3) & 3)) & 3;
            int col = p >> 2;
            const unsigned short* gs = (hi ? Bth : Btl) + (size_t)(bcol + col) * K + k0 + kq * 8;
            gload16(gs, (hi ? sBh : sBl) + s * 1024);
        }
    };

    char* cur = lds;
    char* nxt = lds + BUF;
    stageB(cur, 0);
    stageA(cur, 0);
    __syncthreads();

    const int KT = K / 32;
    for (int t = 0; t < KT; ++t) {
        const int k1 = (t + 1) * 32;
        if (t + 1 < KT) {
            stageB(nxt, k1);
            stageA(nxt, k1);
        }
        {
            char* sAh = cur;
            char* sAl = cur + ABYTES;
            char* sBh = cur + 2 * ABYTES;
            char* sBl = sBh + BBYTES;
            s16x8 fah[FM], fam[FM];
#pragma unroll
            for (int i = 0; i < FM; ++i) {
                int row = wm * 64 + i * 16 + l15;
                int o = row * 64 + (kb ^ (((row >> 1) & 3) << 4));
                fah[i] = *(const s16x8*)(sAh + o);
                fam[i] = *(const s16x8*)(sAl + o);
            }
#pragma unroll
            for (int j = 0; j < FN; ++j) {
                int col = wn * FN * 16 + j * 16 + l15;
                int o = col * 64 + (kb ^ (((col >> 1) & 3) << 4));
                s16x8 fbh = *(const s16x8*)(sBh + o);
                s16x8 fbm = *(const s16x8*)(sBl + o);
#pragma unroll
                for (int i = 0; i < FM; ++i) {
                    acc[i][j] = __builtin_amdgcn_mfma_f32_16x16x32_bf16(fah[i], fbh, acc[i][j], 0, 0, 0);
                    acc[i][j] = __builtin_amdgcn_mfma_f32_16x16x32_bf16(fam[i], fbh, acc[i][j], 0, 0, 0);
                    acc[i][j] = __builtin_amdgcn_mfma_f32_16x16x32_bf16(fah[i], fbm, acc[i][j], 0, 0, 0);
                }
            }
        }
        __syncthreads();
        char* tmp = cur; cur = nxt; nxt = tmp;
    }

#pragma unroll
    for (int i = 0; i < FM; ++i) {
#pragma unroll
        for (int r = 0; r < 4; ++r) {
            int row = brow + wm * 64 + i * 16 + (lane >> 4) * 4 + r;
            if (row >= M) continue;
#pragma unroll
            for (int j = 0; j < FN; ++j) {
                int col = bcol + wn * FN * 16 + j * 16 + l15;
                C[(size_t)row * N + col] = acc[i][j][r];
            }
        }
    }
}

// ---------------- aggregation (+bias, relu) -> bf16 hi/lo planes ----------------
// out[i] = di^2*h[i] + sum_e norm[e]*h[src[e]] + b ; 2-edge unrolled gather.

__global__ void k_agg_split(const float4* __restrict__ h, const int* __restrict__ row_ptr,
                            const int* __restrict__ csr_src, const float* __restrict__ csr_norm,
                            const float* __restrict__ dinv, const float* __restrict__ bias,
                            unsigned short* __restrict__ oh, unsigned short* __restrict__ ol,
                            int n, int f_shift) {
    int idx = blockIdx.x * blockDim.x + threadIdx.x;
    int dout4 = 1 << f_shift;
    int total = n << f_shift;
    if (idx >= total) return;
    int i = idx >> f_shift;
    int f = idx & (dout4 - 1);

    float di = dinv[i];
    float sn = di * di;
    float4 hv = h[(size_t)i * dout4 + f];
    float4 acc;
    acc.x = hv.x * sn; acc.y = hv.y * sn; acc.z = hv.z * sn; acc.w = hv.w * sn;

    int e = row_ptr[i], s1 = row_ptr[i + 1];
    for (; e + 1 < s1; e += 2) {
        int   sa = csr_src[e],      sb = csr_src[e + 1];
        float na = csr_norm[e],     nb = csr_norm[e + 1];
        float4 va = h[(size_t)sa * dout4 + f];
        float4 vb = h[(size_t)sb * dout4 + f];
        acc.x += va.x * na + vb.x * nb;
        acc.y += va.y * na + vb.y * nb;
        acc.z += va.z * na + vb.z * nb;
        acc.w += va.w * na + vb.w * nb;
    }
    if (e < s1) {
        int   s = csr_src[e];
        float nm = csr_norm[e];
        float4 v = h[(size_t)s * dout4 + f];
        acc.x += v.x * nm; acc.y += v.y * nm; acc.z += v.z * nm; acc.w += v.w * nm;
    }

    const float4* b4 = (const float4*)bias;
    float4 b = b4[f];
    float4 o;
    o.x = fmaxf(acc.x + b.x, 0.f);
    o.y = fmaxf(acc.y + b.y, 0.f);
    o.z = fmaxf(acc.z + b.z, 0.f);
    o.w = fmaxf(acc.w + b.w, 0.f);

    short2 p0 = split2(o.x), p1 = split2(o.y), p2 = split2(o.z), p3 = split2(o.w);
    size_t base = ((size_t)i << f_shift << 2) + f * 4;
    *(ushort4*)(oh + base) = make_ushort4((unsigned short)p0.x, (unsigned short)p1.x,
                                          (unsigned short)p2.x, (unsigned short)p3.x);
    *(ushort4*)(ol + base) = make_ushort4((unsigned short)p0.y, (unsigned short)p1.y,
                                          (unsigned short)p2.y, (unsigned short)p3.y);
}

// ---------------- aggregation (+bias), fp32 out (layer 4) ----------------

__global__ void k_agg(const float4* __restrict__ h, const int* __restrict__ row_ptr,
                      const int* __restrict__ csr_src, const float* __restrict__ csr_norm,
                      const float* __restrict__ dinv, const float* __restrict__ bias,
                      float4* __restrict__ out, int n, int f_shift) {
    int idx = blockIdx.x * blockDim.x + threadIdx.x;
    int dout4 = 1 << f_shift;
    int total = n << f_shift;
    if (idx >= total) return;
    int i = idx >> f_shift;
    int f = idx & (dout4 - 1);

    float di = dinv[i];
    float sn = di * di;
    float4 hv = h[(size_t)i * dout4 + f];
    float4 acc;
    acc.x = hv.x * sn; acc.y = hv.y * sn; acc.z = hv.z * sn; acc.w = hv.w * sn;

    int e = row_ptr[i], s1 = row_ptr[i + 1];
    for (; e + 1 < s1; e += 2) {
        int   sa = csr_src[e],      sb = csr_src[e + 1];
        float na = csr_norm[e],     nb = csr_norm[e + 1];
        float4 va = h[(size_t)sa * dout4 + f];
        float4 vb = h[(size_t)sb * dout4 + f];
        acc.x += va.x * na + vb.x * nb;
        acc.y += va.y * na + vb.y * nb;
        acc.z += va.z * na + vb.z * nb;
        acc.w += va.w * na + vb.w * nb;
    }
    if (e < s1) {
        int   s = csr_src[e];
        float nm = csr_norm[e];
        float4 v = h[(size_t)s * dout4 + f];
        acc.x += v.x * nm; acc.y += v.y * nm; acc.z += v.z * nm; acc.w += v.w * nm;
    }

    const float4* b4 = (const float4*)bias;
    float4 b = b4[f];
    float4 o;
    o.x = acc.x + b.x;
    o.y = acc.y + b.y;
    o.z = acc.z + b.z;
    o.w = acc.w + b.w;
    out[(size_t)i * dout4 + f] = o;
}

// ---------------- mean pool per graph (batch sorted) ----------------

__global__ void k_pool(const float* __restrict__ h, const int* __restrict__ batch,
                       int n, float* __restrict__ pooled) {
    int g = blockIdx.x;
    int start, end;
    {
        int lo = 0, hi = n;
        while (lo < hi) { int mid = (lo + hi) >> 1; if (batch[mid] < g) lo = mid + 1; else hi = mid; }
        start = lo;
        lo = start; hi = n;
        while (lo < hi) { int mid = (lo + hi) >> 1; if (batch[mid] < g + 1) lo = mid + 1; else hi = mid; }
        end = lo;
    }
    int f = threadIdx.x & 31;
    int sub = threadIdx.x >> 5;
    float s = 0.f;
    for (int i = start + sub; i < end; i += 8) s += h[(size_t)i * 32 + f];
    __shared__ float red[8][32];
    red[sub][f] = s;
    __syncthreads();
    if (sub == 0) {
        float t = 0.f;
#pragma unroll
        for (int k = 0; k < 8; ++k) t += red[k][f];
        int c = end - start;
        pooled[g * 32 + f] = t / (float)(c > 0 ? c : 1);
    }
}

// ---------------- tiny MLP head ----------------

__global__ void k_mlp(const float* __restrict__ pooled, const float* __restrict__ lw1,
                      const float* __restrict__ lb1, const float* __restrict__ lw2,
                      const float* __restrict__ lb2, float* __restrict__ out, int g_count) {
    int g = threadIdx.x;
    if (g >= g_count) return;
    float p[32];
#pragma unroll
    for (int k = 0; k < 32; ++k) p[k] = pooled[g * 32 + k];
    float hmid[16];
#pragma unroll
    for (int j = 0; j < 16; ++j) {
        float s = lb1[j];
#pragma unroll
        for (int k = 0; k < 32; ++k) s += p[k] * lw1[k * 16 + j];
        hmid[j] = fmaxf(s, 0.f);
    }
#pragma unroll
    for (int o = 0; o < 2; ++o) {
        float s = lb2[o];
#pragma unroll
        for (int k = 0; k < 16; ++k) s += hmid[k] * lw2[k * 2 + o];
        out[g * 2 + o] = s;
    }
}

// ---------------- launch ----------------

extern "C" void kernel_launch(void* const* d_in, const int* in_sizes, int n_in,
                              void* d_out, int out_size, void* d_ws, size_t ws_size,
                              hipStream_t stream) {
    const float* x     = (const float*)d_in[0];
    const int*   ei    = (const int*)d_in[1];
    const int*   batch = (const int*)d_in[2];
    const float* w1 = (const float*)d_in[3];  const float* b1 = (const float*)d_in[4];
    const float* w2 = (const float*)d_in[5];  const float* b2 = (const float*)d_in[6];
    const float* w3 = (const float*)d_in[7];  const float* b3 = (const float*)d_in[8];
    const float* w4 = (const float*)d_in[9];  const float* b4 = (const float*)d_in[10];
    const float* lw1 = (const float*)d_in[11]; const float* lb1 = (const float*)d_in[12];
    const float* lw2 = (const float*)d_in[13]; const float* lb2 = (const float*)d_in[14];
    float* out = (float*)d_out;

    const int n = in_sizes[0] / 512;   // 100000
    const int E = in_sizes[1] / 2;     // 320000
    const int G = 64;

    const int* src = ei;
    const int* dst = ei + E;

    char* ws = (char*)d_ws;
    size_t off = 0;
    auto alloc = [&](size_t bytes) -> void* {
        void* p = ws + off;
        off = (off + bytes + 255) & ~((size_t)255);
        return p;
    };
    float*          bufA = (float*)alloc((size_t)n * 256 * sizeof(float));  // GEMM out
    unsigned short* pAh  = (unsigned short*)alloc((size_t)n * 256 * 2);     // layer planes
    unsigned short* pAl  = (unsigned short*)alloc((size_t)n * 256 * 2);
    int*   cnt      = (int*)alloc((size_t)n * sizeof(int));
    int*   cursor   = (int*)alloc((size_t)n * sizeof(int));
    int*   row_ptr  = (int*)alloc((size_t)(n + 1) * sizeof(int));
    int*   csr      = (int*)alloc((size_t)E * sizeof(int));
    float* csr_norm = (float*)alloc((size_t)E * sizeof(float));
    float* dinv     = (float*)alloc((size_t)n * sizeof(float));
    float* pooled   = (float*)alloc((size_t)G * 32 * sizeof(float));
    int*   bsum     = (int*)alloc(64 * sizeof(int));
    int*   boff     = (int*)alloc(64 * sizeof(int));
    unsigned short* w1h = (unsigned short*)alloc(256 * 512 * 2);
    unsigned short* w1l = (unsigned short*)alloc(256 * 512 * 2);
    unsigned short* w2h = (unsigned short*)alloc(128 * 256 * 2);
    unsigned short* w2l = (unsigned short*)alloc(128 * 256 * 2);
    unsigned short* w3h = (unsigned short*)alloc(64 * 128 * 2);
    unsigned short* w3l = (unsigned short*)alloc(64 * 128 * 2);
    unsigned short* w4h = (unsigned short*)alloc(32 * 64 * 2);
    unsigned short* w4l = (unsigned short*)alloc(32 * 64 * 2);
    // layer-4 fp32 agg output parked in pAl beyond the live d=64 plane region
    float* bufB = (float*)(pAl + (size_t)n * 64);
    (void)ws_size;

    // NOTE: n*sizeof(int) is NOT a 256B multiple — zero each separately (r11 lesson).
    hipMemsetAsync(cnt, 0, (size_t)n * sizeof(int), stream);
    hipMemsetAsync(cursor, 0, (size_t)n * sizeof(int), stream);

    // fused weight pre-split (1 launch)
    k_split_w_all<<<(174080 + 255) / 256, 256, 0, stream>>>(
        w1, w2, w3, w4, w1h, w1l, w2h, w2l, w3h, w3l, w4h, w4l);

    const int nscan = (n + 4095) / 4096;
    k_count<<<(E + 255) / 256, 256, 0, stream>>>(dst, E, cnt);
    k_dinv <<<(n + 255) / 256, 256, 0, stream>>>(cnt, n, dinv);
    k_scan_sums   <<<nscan, 256, 0, stream>>>(cnt, n, bsum);
    k_scan_offsets<<<1, 64, 0, stream>>>(bsum, nscan, boff, row_ptr + n);
    k_scan_final  <<<nscan, 256, 0, stream>>>(cnt, n, boff, row_ptr);
    k_fill<<<(E + 255) / 256, 256, 0, stream>>>(src, dst, E, row_ptr, cursor, dinv, csr, csr_norm);

    const int gy = (n + 127) / 128;   // 782, BM=128

    // layer 1: [n,512]@[512,256], BN=128, dbuf + X-2-ahead, x split in-kernel
    k_gemm1<<<dim3(2, gy), 256, 0, stream>>>(x, w1h, w1l, bufA, n);
    k_agg_split<<<((size_t)n * 64 + 255) / 256, 256, 0, stream>>>(
        (const float4*)bufA, row_ptr, csr, csr_norm, dinv, b1, pAh, pAl, n, 6);

    // layer 2: [n,256]@[256,128]
    k_gemm<4><<<dim3(1, gy), 256, 0, stream>>>(pAh, pAl, w2h, w2l, bufA, n, 256, 128);
    k_agg_split<<<((size_t)n * 32 + 255) / 256, 256, 0, stream>>>(
        (const float4*)bufA, row_ptr, csr, csr_norm, dinv, b2, pAh, pAl, n, 5);

    // layer 3: [n,128]@[128,64]
    k_gemm<2><<<dim3(1, gy), 256, 0, stream>>>(pAh, pAl, w3h, w3l, bufA, n, 128, 64);
    k_agg_split<<<((size_t)n * 16 + 255) / 256, 256, 0, stream>>>(
        (const float4*)bufA, row_ptr, csr, csr_norm, dinv, b3, pAh, pAl, n, 4);

    // layer 4: [n,64]@[64,32] (no relu)
    k_gemm<1><<<dim3(1, gy), 256, 0, stream>>>(pAh, pAl, w4h, w4l, bufA, n, 64, 32);
    k_agg<<<((size_t)n * 8 + 255) / 256, 256, 0, stream>>>(
        (const float4*)bufA, row_ptr, csr, csr_norm, dinv, b4, (float4*)bufB, n, 3);

    k_pool<<<G, 256, 0, stream>>>(bufB, batch, n, pooled);
    k_mlp<<<1, 64, 0, stream>>>(pooled, lw1, lb1, lw2, lb2, out, G);
}

// Round 14
// 481.210 us; speedup vs baseline: 1.0647x; 1.0088x over previous
//
#include <hip/hip_runtime.h>
#include <cstdint>
#include <cstddef>

// GCN: 4x GCNConv (512->256->128->64->32) + mean-pool + 2-layer MLP.
// Round 14: GEMM epilogues emit bf16 hi/lo planes; aggregation gathers
// neighbors from the hi plane only (half the gather bytes; self term exact).
// GEMM schedules unchanged from r13.

typedef __attribute__((ext_vector_type(8))) short s16x8;
typedef __attribute__((ext_vector_type(4))) float f32x4;

// fp32 -> (bf16 hi, bf16 lo) by truncation; lo captures the truncation error.
__device__ __forceinline__ short2 split2(float f) {
    union { float f; unsigned u; } c; c.f = f;
    short hi = (short)(c.u >> 16);
    union { unsigned u; float f; } h; h.u = c.u & 0xffff0000u;
    union { float f; unsigned u; } r; r.f = f - h.f;
    short lo = (short)(r.u >> 16);
    return make_short2(hi, lo);
}

__device__ __forceinline__ float bf2f(unsigned short u) {
    union { unsigned v; float f; } c; c.v = ((unsigned)u) << 16; return c.f;
}

// async 16B global -> LDS (wave-uniform LDS base; HW adds lane*16)
__device__ __forceinline__ void gload16(const void* g, void* l) {
    __builtin_amdgcn_global_load_lds(
        (const __attribute__((address_space(1))) unsigned int*)g,
        (__attribute__((address_space(3))) unsigned int*)l, 16, 0, 0);
}

// ---------------- CSR build ----------------

__global__ void k_count(const int* __restrict__ dst, int E, int* __restrict__ cnt) {
    int e = blockIdx.x * blockDim.x + threadIdx.x;
    if (e < E) atomicAdd(&cnt[dst[e]], 1);
}

__global__ void k_dinv(const int* __restrict__ cnt, int n, float* __restrict__ dinv) {
    int i = blockIdx.x * blockDim.x + threadIdx.x;
    if (i < n) dinv[i] = rsqrtf((float)(cnt[i] + 1));
}

__global__ void k_scan_sums(const int* __restrict__ cnt, int n, int* __restrict__ bsum) {
    __shared__ int s[256];
    int t = threadIdx.x;
    int base = blockIdx.x * 4096 + t * 16;
    int sum = 0;
#pragma unroll
    for (int j = 0; j < 16; ++j) { int i = base + j; if (i < n) sum += cnt[i]; }
    s[t] = sum;
    __syncthreads();
    for (int off = 128; off > 0; off >>= 1) {
        if (t < off) s[t] += s[t + off];
        __syncthreads();
    }
    if (t == 0) bsum[blockIdx.x] = s[0];
}

__global__ void k_scan_offsets(const int* __restrict__ bsum, int nb,
                               int* __restrict__ boff, int* __restrict__ totalp) {
    int t = threadIdx.x;   // 64 threads
    int v = (t < nb) ? bsum[t] : 0;
    int x = v;
    for (int off = 1; off < 64; off <<= 1) {
        int y = __shfl_up(x, off);
        if (t >= off) x += y;
    }
    if (t < nb) boff[t] = x - v;
    if (t == 63) *totalp = x;
}

__global__ void k_scan_final(const int* __restrict__ cnt, int n,
                             const int* __restrict__ boff, int* __restrict__ row_ptr) {
    __shared__ int s[256];
    int t = threadIdx.x;
    int base = blockIdx.x * 4096 + t * 16;
    int v[16]; int sum = 0;
#pragma unroll
    for (int j = 0; j < 16; ++j) { int i = base + j; v[j] = (i < n) ? cnt[i] : 0; sum += v[j]; }
    s[t] = sum;
    __syncthreads();
    for (int off = 1; off < 256; off <<= 1) {
        int y = (t >= off) ? s[t - off] : 0;
        __syncthreads();
        s[t] += y;
        __syncthreads();
    }
    int run = boff[blockIdx.x] + ((t == 0) ? 0 : s[t - 1]);
#pragma unroll
    for (int j = 0; j < 16; ++j) {
        int i = base + j;
        if (i < n) row_ptr[i] = run;
        run += v[j];
    }
}

// fill CSR and the per-edge normalization weight norm = dinv[src]*dinv[dst]
__global__ void k_fill(const int* __restrict__ src, const int* __restrict__ dst, int E,
                       const int* __restrict__ row_ptr, int* __restrict__ cursor,
                       const float* __restrict__ dinv,
                       int* __restrict__ csr_src, float* __restrict__ csr_norm) {
    int e = blockIdx.x * blockDim.x + threadIdx.x;
    if (e >= E) return;
    int d = dst[e];
    int s = src[e];
    int p = atomicAdd(&cursor[d], 1);
    int slot = row_ptr[d] + p;
    csr_src[slot]  = s;
    csr_norm[slot] = dinv[s] * dinv[d];
}

// ------- fused weight pre-split: all 4 layers in one launch -------

__global__ void k_split_w_all(const float* __restrict__ w1, const float* __restrict__ w2,
                              const float* __restrict__ w3, const float* __restrict__ w4,
                              unsigned short* __restrict__ w1h, unsigned short* __restrict__ w1l,
                              unsigned short* __restrict__ w2h, unsigned short* __restrict__ w2l,
                              unsigned short* __restrict__ w3h, unsigned short* __restrict__ w3l,
                              unsigned short* __restrict__ w4h, unsigned short* __restrict__ w4l) {
    int idx = blockIdx.x * blockDim.x + threadIdx.x;
    const float* w; unsigned short *th, *tl; int N, ks, loc;
    if (idx < 131072)      { w = w1; th = w1h; tl = w1l; N = 256; ks = 9; loc = idx; }
    else if (idx < 163840) { w = w2; th = w2h; tl = w2l; N = 128; ks = 8; loc = idx - 131072; }
    else if (idx < 172032) { w = w3; th = w3h; tl = w3l; N = 64;  ks = 7; loc = idx - 163840; }
    else if (idx < 174080) { w = w4; th = w4h; tl = w4l; N = 32;  ks = 6; loc = idx - 172032; }
    else return;
    int nn = loc >> ks;
    int k  = loc & ((1 << ks) - 1);
    short2 p = split2(w[(size_t)k * N + nn]);
    th[loc] = (unsigned short)p.x;
    tl[loc] = (unsigned short)p.y;
}

// ---------------- layer-1 GEMM: dbuf + X 2-steps-ahead; bf16-plane epilogue ----------------

__global__ __launch_bounds__(256)
void k_gemm1(const float* __restrict__ A32,
             const unsigned short* __restrict__ Bth, const unsigned short* __restrict__ Btl,
             unsigned short* __restrict__ Chi, unsigned short* __restrict__ Clo, int M) {
    constexpr int K = 512, KT = 16;
    constexpr int APL = 128 * 64;   // 8KB per A plane
    constexpr int BPL = 128 * 64;
    __shared__ char sA[2][2 * APL];  // [buf][hi|lo]
    __shared__ char sB[2][2 * BPL];

    const int tid  = threadIdx.x;
    const int lane = tid & 63;
    const int w    = tid >> 6;
    const int wm   = w & 1;
    const int wn   = w >> 1;
    const int brow = blockIdx.y * 128;
    const int bcol = blockIdx.x * 128;
    const int l15  = lane & 15;
    const int kb   = (lane >> 4) * 16;

    const int arow  = tid >> 1;
    const int ahalf = tid & 1;
    int ag = brow + arow; if (ag > M - 1) ag = M - 1;   // clamp: dup rows only feed C rows >= M
    const float* xrow = A32 + (size_t)ag * K + ahalf * 16;
    const int vq = (arow >> 1) & 3;
    const int q0 = ((2 * ahalf) ^ vq) * 16;
    const int q1 = ((2 * ahalf + 1) ^ vq) * 16;

    f32x4 acc[4][4];
#pragma unroll
    for (int i = 0; i < 4; ++i)
#pragma unroll
        for (int j = 0; j < 4; ++j) acc[i][j] = (f32x4){0.f, 0.f, 0.f, 0.f};

    float4 xr[2][4];   // ping-pong X reg sets; loop fully unrolled -> static idx

    auto X = [&](int t, int p) {
        const float4* q = (const float4*)(xrow + t * 32);
        xr[p][0] = q[0]; xr[p][1] = q[1]; xr[p][2] = q[2]; xr[p][3] = q[3];
    };
    auto WA = [&](char* abuf, int p) {
        float v[16] = {xr[p][0].x, xr[p][0].y, xr[p][0].z, xr[p][0].w,
                       xr[p][1].x, xr[p][1].y, xr[p][1].z, xr[p][1].w,
                       xr[p][2].x, xr[p][2].y, xr[p][2].z, xr[p][2].w,
                       xr[p][3].x, xr[p][3].y, xr[p][3].z, xr[p][3].w};
        s16x8 h0, h1, l0, l1;
#pragma unroll
        for (int j = 0; j < 8; ++j) { short2 q = split2(v[j]);     h0[j] = q.x; l0[j] = q.y; }
#pragma unroll
        for (int j = 0; j < 8; ++j) { short2 q = split2(v[8 + j]); h1[j] = q.x; l1[j] = q.y; }
        *(s16x8*)(abuf + arow * 64 + q0)       = h0;
        *(s16x8*)(abuf + arow * 64 + q1)       = h1;
        *(s16x8*)(abuf + APL + arow * 64 + q0) = l0;
        *(s16x8*)(abuf + APL + arow * 64 + q1) = l1;
    };
    auto SB = [&](char* bbuf, int t) {
#pragma unroll
        for (int u = 0; u < 4; ++u) {
            int id = w + u * 4;                 // 0..15
            int hi = (id < 8) ? 1 : 0;
            int s  = hi ? id : id - 8;
            int p  = s * 64 + lane;
            int kq = (p ^ ((p >> 3) & 3)) & 3;
            int col = p >> 2;
            const unsigned short* gs = (hi ? Bth : Btl) + (size_t)(bcol + col) * K + t * 32 + kq * 8;
            gload16(gs, (hi ? bbuf : bbuf + BPL) + s * 1024);
        }
    };
    auto MM = [&](char* abuf, char* bbuf) {
        char* sAl = abuf + APL;
        char* sBl = bbuf + BPL;
        s16x8 fah[4], fam[4];
#pragma unroll
        for (int i = 0; i < 4; ++i) {
            int row = wm * 64 + i * 16 + l15;
            int o = row * 64 + (kb ^ (((row >> 1) & 3) << 4));
            fah[i] = *(const s16x8*)(abuf + o);
            fam[i] = *(const s16x8*)(sAl + o);
        }
#pragma unroll
        for (int j = 0; j < 4; ++j) {
            int col = wn * 64 + j * 16 + l15;
            int o = col * 64 + (kb ^ (((col >> 1) & 3) << 4));
            s16x8 fbh = *(const s16x8*)(bbuf + o);
            s16x8 fbm = *(const s16x8*)(sBl + o);
#pragma unroll
            for (int i = 0; i < 4; ++i) {
                acc[i][j] = __builtin_amdgcn_mfma_f32_16x16x32_bf16(fah[i], fbh, acc[i][j], 0, 0, 0);
                acc[i][j] = __builtin_amdgcn_mfma_f32_16x16x32_bf16(fam[i], fbh, acc[i][j], 0, 0, 0);
                acc[i][j] = __builtin_amdgcn_mfma_f32_16x16x32_bf16(fah[i], fbm, acc[i][j], 0, 0, 0);
            }
        }
    };

    // prologue
    X(0, 0);
    X(1, 1);
    SB(sB[0], 0);
    WA(sA[0], 0);
    __syncthreads();

#pragma unroll
    for (int t = 0; t < KT; ++t) {
        if (t + 2 < KT) X(t + 2, t & 1);
        if (t + 1 < KT) SB(sB[(t + 1) & 1], t + 1);
        MM(sA[t & 1], sB[t & 1]);
        if (t + 1 < KT) WA(sA[(t + 1) & 1], (t + 1) & 1);
        __syncthreads();
    }

    // C/D layout: col = lane&15, row = (lane>>4)*4 + reg; emit hi/lo planes
#pragma unroll
    for (int i = 0; i < 4; ++i) {
#pragma unroll
        for (int r = 0; r < 4; ++r) {
            int row = brow + wm * 64 + i * 16 + (lane >> 4) * 4 + r;
            if (row >= M) continue;
#pragma unroll
            for (int j = 0; j < 4; ++j) {
                int col = bcol + wn * 64 + j * 16 + l15;
                short2 pq = split2(acc[i][j][r]);
                Chi[(size_t)row * 256 + col] = (unsigned short)pq.x;
                Clo[(size_t)row * 256 + col] = (unsigned short)pq.y;
            }
        }
    }
}

// ---------------- 2-phase dbuf split-bf16 MFMA GEMM (layers 2-4) ----------------

template <int FN>
__global__ __launch_bounds__(256)
void k_gemm(const unsigned short* __restrict__ Ah, const unsigned short* __restrict__ Al,
            const unsigned short* __restrict__ Bth, const unsigned short* __restrict__ Btl,
            unsigned short* __restrict__ Chi, unsigned short* __restrict__ Clo,
            int M, int K, int N) {
    constexpr int FM = 4;
    constexpr int BM = 128;
    constexpr int BN = FN * 32;
    constexpr int ABYTES = BM * 64;
    constexpr int BBYTES = BN * 64;
    constexpr int BUF = 2 * ABYTES + 2 * BBYTES;
    __shared__ char lds[2 * BUF];

    const int tid  = threadIdx.x;
    const int lane = tid & 63;
    const int w    = tid >> 6;
    const int wm   = w & 1;
    const int wn   = w >> 1;
    const int brow = blockIdx.y * BM;
    const int bcol = blockIdx.x * BN;
    const int l15  = lane & 15;
    const int kb   = (lane >> 4) * 16;

    f32x4 acc[FM][FN];
#pragma unroll
    for (int i = 0; i < FM; ++i)
#pragma unroll
        for (int j = 0; j < FN; ++j) acc[i][j] = (f32x4){0.f, 0.f, 0.f, 0.f};

    auto stageA = [&](char* base, int k0) {
#pragma unroll
        for (int u = 0; u < 4; ++u) {
            int id = w + u * 4;
            int hi = (id < 8) ? 1 : 0;
            int s  = hi ? id : id - 8;
            int p  = s * 64 + lane;
            int kq = (p ^ ((p >> 3) & 3)) & 3;
            int row = p >> 2;
            const unsigned short* gs = (hi ? Ah : Al) + (size_t)(brow + row) * K + k0 + kq * 8;
            gload16(gs, base + (hi ? 0 : ABYTES) + s * 1024);
        }
    };
    auto stageB = [&](char* base, int k0) {
        char* sBh = base + 2 * ABYTES;
        char* sBl = sBh + BBYTES;
#pragma unroll
        for (int u = 0; u < BN / 32; ++u) {
            int id = w + u * 4;
            int hi = (id < BN / 16) ? 1 : 0;
            int s  = hi ? id : id - BN / 16;
            int p  = s * 64 + lane;
            int kq = (p ^ ((p >> 3) & 3)) & 3;
            int col = p >> 2;
            const unsigned short* gs = (hi ? Bth : Btl) + (size_t)(bcol + col) * K + k0 + kq * 8;
            gload16(gs, (hi ? sBh : sBl) + s * 1024);
        }
    };

    char* cur = lds;
    char* nxt = lds + BUF;
    stageB(cur, 0);
    stageA(cur, 0);
    __syncthreads();

    const int KT = K / 32;
    for (int t = 0; t < KT; ++t) {
        const int k1 = (t + 1) * 32;
        if (t + 1 < KT) {
            stageB(nxt, k1);
            stageA(nxt, k1);
        }
        {
            char* sAh = cur;
            char* sAl = cur + ABYTES;
            char* sBh = cur + 2 * ABYTES;
            char* sBl = sBh + BBYTES;
            s16x8 fah[FM], fam[FM];
#pragma unroll
            for (int i = 0; i < FM; ++i) {
                int row = wm * 64 + i * 16 + l15;
                int o = row * 64 + (kb ^ (((row >> 1) & 3) << 4));
                fah[i] = *(const s16x8*)(sAh + o);
                fam[i] = *(const s16x8*)(sAl + o);
            }
#pragma unroll
            for (int j = 0; j < FN; ++j) {
                int col = wn * FN * 16 + j * 16 + l15;
                int o = col * 64 + (kb ^ (((col >> 1) & 3) << 4));
                s16x8 fbh = *(const s16x8*)(sBh + o);
                s16x8 fbm = *(const s16x8*)(sBl + o);
#pragma unroll
                for (int i = 0; i < FM; ++i) {
                    acc[i][j] = __builtin_amdgcn_mfma_f32_16x16x32_bf16(fah[i], fbh, acc[i][j], 0, 0, 0);
                    acc[i][j] = __builtin_amdgcn_mfma_f32_16x16x32_bf16(fam[i], fbh, acc[i][j], 0, 0, 0);
                    acc[i][j] = __builtin_amdgcn_mfma_f32_16x16x32_bf16(fah[i], fbm, acc[i][j], 0, 0, 0);
                }
            }
        }
        __syncthreads();
        char* tmp = cur; cur = nxt; nxt = tmp;
    }

#pragma unroll
    for (int i = 0; i < FM; ++i) {
#pragma unroll
        for (int r = 0; r < 4; ++r) {
            int row = brow + wm * 64 + i * 16 + (lane >> 4) * 4 + r;
            if (row >= M) continue;
#pragma unroll
            for (int j = 0; j < FN; ++j) {
                int col = bcol + wn * FN * 16 + j * 16 + l15;
                short2 pq = split2(acc[i][j][r]);
                Chi[(size_t)row * N + col] = (unsigned short)pq.x;
                Clo[(size_t)row * N + col] = (unsigned short)pq.y;
            }
        }
    }
}

// ---------------- aggregation (+bias, relu) -> bf16 hi/lo planes ----------------
// out[i] = di^2*h[i](hi+lo) + sum_e norm[e]*hi(h[src[e]]) + b
// neighbor gather from hi plane only (half bytes); self term exact.

__global__ void k_agg_split(const unsigned short* __restrict__ hhi,
                            const unsigned short* __restrict__ hlo,
                            const int* __restrict__ row_ptr,
                            const int* __restrict__ csr_src, const float* __restrict__ csr_norm,
                            const float* __restrict__ dinv, const float* __restrict__ bias,
                            unsigned short* __restrict__ oh, unsigned short* __restrict__ ol,
                            int n, int f_shift) {
    int idx = blockIdx.x * blockDim.x + threadIdx.x;
    int dout4 = 1 << f_shift;            // row length in 4-element chunks
    int total = n << f_shift;
    if (idx >= total) return;
    int i = idx >> f_shift;
    int f = idx & (dout4 - 1);
    const int drow = dout4 * 4;          // row length in elements
    size_t ebase = (size_t)i * drow + f * 4;

    float di = dinv[i];
    float sn = di * di;
    ushort4 sh = *(const ushort4*)(hhi + ebase);
    ushort4 sl = *(const ushort4*)(hlo + ebase);
    float4 acc;
    acc.x = (bf2f(sh.x) + bf2f(sl.x)) * sn;
    acc.y = (bf2f(sh.y) + bf2f(sl.y)) * sn;
    acc.z = (bf2f(sh.z) + bf2f(sl.z)) * sn;
    acc.w = (bf2f(sh.w) + bf2f(sl.w)) * sn;

    int e = row_ptr[i], s1 = row_ptr[i + 1];
    for (; e + 1 < s1; e += 2) {
        int   sa = csr_src[e],      sb = csr_src[e + 1];
        float na = csr_norm[e],     nb = csr_norm[e + 1];
        ushort4 va = *(const ushort4*)(hhi + (size_t)sa * drow + f * 4);
        ushort4 vb = *(const ushort4*)(hhi + (size_t)sb * drow + f * 4);
        acc.x += bf2f(va.x) * na + bf2f(vb.x) * nb;
        acc.y += bf2f(va.y) * na + bf2f(vb.y) * nb;
        acc.z += bf2f(va.z) * na + bf2f(vb.z) * nb;
        acc.w += bf2f(va.w) * na + bf2f(vb.w) * nb;
    }
    if (e < s1) {
        int   s = csr_src[e];
        float nm = csr_norm[e];
        ushort4 v = *(const ushort4*)(hhi + (size_t)s * drow + f * 4);
        acc.x += bf2f(v.x) * nm; acc.y += bf2f(v.y) * nm;
        acc.z += bf2f(v.z) * nm; acc.w += bf2f(v.w) * nm;
    }

    const float4* b4 = (const float4*)bias;
    float4 b = b4[f];
    float4 o;
    o.x = fmaxf(acc.x + b.x, 0.f);
    o.y = fmaxf(acc.y + b.y, 0.f);
    o.z = fmaxf(acc.z + b.z, 0.f);
    o.w = fmaxf(acc.w + b.w, 0.f);

    short2 p0 = split2(o.x), p1 = split2(o.y), p2 = split2(o.z), p3 = split2(o.w);
    *(ushort4*)(oh + ebase) = make_ushort4((unsigned short)p0.x, (unsigned short)p1.x,
                                           (unsigned short)p2.x, (unsigned short)p3.x);
    *(ushort4*)(ol + ebase) = make_ushort4((unsigned short)p0.y, (unsigned short)p1.y,
                                           (unsigned short)p2.y, (unsigned short)p3.y);
}

// ---------------- aggregation (+bias), fp32 out (layer 4) ----------------

__global__ void k_agg(const unsigned short* __restrict__ hhi,
                      const unsigned short* __restrict__ hlo,
                      const int* __restrict__ row_ptr,
                      const int* __restrict__ csr_src, const float* __restrict__ csr_norm,
                      const float* __restrict__ dinv, const float* __restrict__ bias,
                      float4* __restrict__ out, int n, int f_shift) {
    int idx = blockIdx.x * blockDim.x + threadIdx.x;
    int dout4 = 1 << f_shift;
    int total = n << f_shift;
    if (idx >= total) return;
    int i = idx >> f_shift;
    int f = idx & (dout4 - 1);
    const int drow = dout4 * 4;
    size_t ebase = (size_t)i * drow + f * 4;

    float di = dinv[i];
    float sn = di * di;
    ushort4 sh = *(const ushort4*)(hhi + ebase);
    ushort4 sl = *(const ushort4*)(hlo + ebase);
    float4 acc;
    acc.x = (bf2f(sh.x) + bf2f(sl.x)) * sn;
    acc.y = (bf2f(sh.y) + bf2f(sl.y)) * sn;
    acc.z = (bf2f(sh.z) + bf2f(sl.z)) * sn;
    acc.w = (bf2f(sh.w) + bf2f(sl.w)) * sn;

    int e = row_ptr[i], s1 = row_ptr[i + 1];
    for (; e + 1 < s1; e += 2) {
        int   sa = csr_src[e],      sb = csr_src[e + 1];
        float na = csr_norm[e],     nb = csr_norm[e + 1];
        ushort4 va = *(const ushort4*)(hhi + (size_t)sa * drow + f * 4);
        ushort4 vb = *(const ushort4*)(hhi + (size_t)sb * drow + f * 4);
        acc.x += bf2f(va.x) * na + bf2f(vb.x) * nb;
        acc.y += bf2f(va.y) * na + bf2f(vb.y) * nb;
        acc.z += bf2f(va.z) * na + bf2f(vb.z) * nb;
        acc.w += bf2f(va.w) * na + bf2f(vb.w) * nb;
    }
    if (e < s1) {
        int   s = csr_src[e];
        float nm = csr_norm[e];
        ushort4 v = *(const ushort4*)(hhi + (size_t)s * drow + f * 4);
        acc.x += bf2f(v.x) * nm; acc.y += bf2f(v.y) * nm;
        acc.z += bf2f(v.z) * nm; acc.w += bf2f(v.w) * nm;
    }

    const float4* b4 = (const float4*)bias;
    float4 b = b4[f];
    float4 o;
    o.x = acc.x + b.x;
    o.y = acc.y + b.y;
    o.z = acc.z + b.z;
    o.w = acc.w + b.w;
    out[(size_t)i * dout4 + f] = o;
}

// ---------------- mean pool per graph (batch sorted) ----------------

__global__ void k_pool(const float* __restrict__ h, const int* __restrict__ batch,
                       int n, float* __restrict__ pooled) {
    int g = blockIdx.x;
    int start, end;
    {
        int lo = 0, hi = n;
        while (lo < hi) { int mid = (lo + hi) >> 1; if (batch[mid] < g) lo = mid + 1; else hi = mid; }
        start = lo;
        lo = start; hi = n;
        while (lo < hi) { int mid = (lo + hi) >> 1; if (batch[mid] < g + 1) lo = mid + 1; else hi = mid; }
        end = lo;
    }
    int f = threadIdx.x & 31;
    int sub = threadIdx.x >> 5;
    float s = 0.f;
    for (int i = start + sub; i < end; i += 8) s += h[(size_t)i * 32 + f];
    __shared__ float red[8][32];
    red[sub][f] = s;
    __syncthreads();
    if (sub == 0) {
        float t = 0.f;
#pragma unroll
        for (int k = 0; k < 8; ++k) t += red[k][f];
        int c = end - start;
        pooled[g * 32 + f] = t / (float)(c > 0 ? c : 1);
    }
}

// ---------------- tiny MLP head ----------------

__global__ void k_mlp(const float* __restrict__ pooled, const float* __restrict__ lw1,
                      const float* __restrict__ lb1, const float* __restrict__ lw2,
                      const float* __restrict__ lb2, float* __restrict__ out, int g_count) {
    int g = threadIdx.x;
    if (g >= g_count) return;
    float p[32];
#pragma unroll
    for (int k = 0; k < 32; ++k) p[k] = pooled[g * 32 + k];
    float hmid[16];
#pragma unroll
    for (int j = 0; j < 16; ++j) {
        float s = lb1[j];
#pragma unroll
        for (int k = 0; k < 32; ++k) s += p[k] * lw1[k * 16 + j];
        hmid[j] = fmaxf(s, 0.f);
    }
#pragma unroll
    for (int o = 0; o < 2; ++o) {
        float s = lb2[o];
#pragma unroll
        for (int k = 0; k < 16; ++k) s += hmid[k] * lw2[k * 2 + o];
        out[g * 2 + o] = s;
    }
}

// ---------------- launch ----------------

extern "C" void kernel_launch(void* const* d_in, const int* in_sizes, int n_in,
                              void* d_out, int out_size, void* d_ws, size_t ws_size,
                              hipStream_t stream) {
    const float* x     = (const float*)d_in[0];
    const int*   ei    = (const int*)d_in[1];
    const int*   batch = (const int*)d_in[2];
    const float* w1 = (const float*)d_in[3];  const float* b1 = (const float*)d_in[4];
    const float* w2 = (const float*)d_in[5];  const float* b2 = (const float*)d_in[6];
    const float* w3 = (const float*)d_in[7];  const float* b3 = (const float*)d_in[8];
    const float* w4 = (const float*)d_in[9];  const float* b4 = (const float*)d_in[10];
    const float* lw1 = (const float*)d_in[11]; const float* lb1 = (const float*)d_in[12];
    const float* lw2 = (const float*)d_in[13]; const float* lb2 = (const float*)d_in[14];
    float* out = (float*)d_out;

    const int n = in_sizes[0] / 512;   // 100000
    const int E = in_sizes[1] / 2;     // 320000
    const int G = 64;

    const int* src = ei;
    const int* dst = ei + E;

    char* ws = (char*)d_ws;
    size_t off = 0;
    auto alloc = [&](size_t bytes) -> void* {
        void* p = ws + off;
        off = (off + bytes + 255) & ~((size_t)255);
        return p;
    };
    unsigned short* ghi  = (unsigned short*)alloc((size_t)n * 256 * 2);  // GEMM out hi plane
    unsigned short* glo  = (unsigned short*)alloc((size_t)n * 256 * 2);  // GEMM out lo plane
    unsigned short* pAh  = (unsigned short*)alloc((size_t)n * 256 * 2);  // agg-out planes
    unsigned short* pAl  = (unsigned short*)alloc((size_t)n * 256 * 2);
    int*   cnt      = (int*)alloc((size_t)n * sizeof(int));
    int*   cursor   = (int*)alloc((size_t)n * sizeof(int));
    int*   row_ptr  = (int*)alloc((size_t)(n + 1) * sizeof(int));
    int*   csr      = (int*)alloc((size_t)E * sizeof(int));
    float* csr_norm = (float*)alloc((size_t)E * sizeof(float));
    float* dinv     = (float*)alloc((size_t)n * sizeof(float));
    float* pooled   = (float*)alloc((size_t)G * 32 * sizeof(float));
    int*   bsum     = (int*)alloc(64 * sizeof(int));
    int*   boff     = (int*)alloc(64 * sizeof(int));
    unsigned short* w1h = (unsigned short*)alloc(256 * 512 * 2);
    unsigned short* w1l = (unsigned short*)alloc(256 * 512 * 2);
    unsigned short* w2h = (unsigned short*)alloc(128 * 256 * 2);
    unsigned short* w2l = (unsigned short*)alloc(128 * 256 * 2);
    unsigned short* w3h = (unsigned short*)alloc(64 * 128 * 2);
    unsigned short* w3l = (unsigned short*)alloc(64 * 128 * 2);
    unsigned short* w4h = (unsigned short*)alloc(32 * 64 * 2);
    unsigned short* w4l = (unsigned short*)alloc(32 * 64 * 2);
    // layer-4 fp32 agg output parked in pAl beyond the live d=64 plane region
    float* bufB = (float*)(pAl + (size_t)n * 64);
    (void)ws_size;

    // NOTE: n*sizeof(int) is NOT a 256B multiple — zero each separately (r11 lesson).
    hipMemsetAsync(cnt, 0, (size_t)n * sizeof(int), stream);
    hipMemsetAsync(cursor, 0, (size_t)n * sizeof(int), stream);

    // fused weight pre-split (1 launch)
    k_split_w_all<<<(174080 + 255) / 256, 256, 0, stream>>>(
        w1, w2, w3, w4, w1h, w1l, w2h, w2l, w3h, w3l, w4h, w4l);

    const int nscan = (n + 4095) / 4096;
    k_count<<<(E + 255) / 256, 256, 0, stream>>>(dst, E, cnt);
    k_dinv <<<(n + 255) / 256, 256, 0, stream>>>(cnt, n, dinv);
    k_scan_sums   <<<nscan, 256, 0, stream>>>(cnt, n, bsum);
    k_scan_offsets<<<1, 64, 0, stream>>>(bsum, nscan, boff, row_ptr + n);
    k_scan_final  <<<nscan, 256, 0, stream>>>(cnt, n, boff, row_ptr);
    k_fill<<<(E + 255) / 256, 256, 0, stream>>>(src, dst, E, row_ptr, cursor, dinv, csr, csr_norm);

    const int gy = (n + 127) / 128;   // 782, BM=128

    // layer 1: [n,512]@[512,256], BN=128, dbuf + X-2-ahead, x split in-kernel
    k_gemm1<<<dim3(2, gy), 256, 0, stream>>>(x, w1h, w1l, ghi, glo, n);
    k_agg_split<<<((size_t)n * 64 + 255) / 256, 256, 0, stream>>>(
        ghi, glo, row_ptr, csr, csr_norm, dinv, b1, pAh, pAl, n, 6);

    // layer 2: [n,256]@[256,128]
    k_gemm<4><<<dim3(1, gy), 256, 0, stream>>>(pAh, pAl, w2h, w2l, ghi, glo, n, 256, 128);
    k_agg_split<<<((size_t)n * 32 + 255) / 256, 256, 0, stream>>>(
        ghi, glo, row_ptr, csr, csr_norm, dinv, b2, pAh, pAl, n, 5);

    // layer 3: [n,128]@[128,64]
    k_gemm<2><<<dim3(1, gy), 256, 0, stream>>>(pAh, pAl, w3h, w3l, ghi, glo, n, 128, 64);
    k_agg_split<<<((size_t)n * 16 + 255) / 256, 256, 0, stream>>>(
        ghi, glo, row_ptr, csr, csr_norm, dinv, b3, pAh, pAl, n, 4);

    // layer 4: [n,64]@[64,32] (no relu)
    k_gemm<1><<<dim3(1, gy), 256, 0, stream>>>(pAh, pAl, w4h, w4l, ghi, glo, n, 64, 32);
    k_agg<<<((size_t)n * 8 + 255) / 256, 256, 0, stream>>>(
        ghi, glo, row_ptr, csr, csr_norm, dinv, b4, (float4*)bufB, n, 3);

    k_pool<<<G, 256, 0, stream>>>(bufB, batch, n, pooled);
    k_mlp<<<1, 64, 0, stream>>>(pooled, lw1, lb1, lw2, lb2, out, G);
}

// Round 15
// 475.461 us; speedup vs baseline: 1.0776x; 1.0121x over previous
//
#include <hip/hip_runtime.h>
#include <cstdint>
#include <cstddef>

// GCN: 4x GCNConv (512->256->128->64->32) + mean-pool + 2-layer MLP.
// Round 15: layers 2-4 GEMM switched to BM=64 (1563 blocks -> ~2% tail vs
// 35% at BM=128; LDS 48/32/24KB -> 3-6 blocks/CU). k_dinv folded into
// k_scan_final. GEMM1 + aggs unchanged from r14.

typedef __attribute__((ext_vector_type(8))) short s16x8;
typedef __attribute__((ext_vector_type(4))) float f32x4;

// fp32 -> (bf16 hi, bf16 lo) by truncation; lo captures the truncation error.
__device__ __forceinline__ short2 split2(float f) {
    union { float f; unsigned u; } c; c.f = f;
    short hi = (short)(c.u >> 16);
    union { unsigned u; float f; } h; h.u = c.u & 0xffff0000u;
    union { float f; unsigned u; } r; r.f = f - h.f;
    short lo = (short)(r.u >> 16);
    return make_short2(hi, lo);
}

__device__ __forceinline__ float bf2f(unsigned short u) {
    union { unsigned v; float f; } c; c.v = ((unsigned)u) << 16; return c.f;
}

// async 16B global -> LDS (wave-uniform LDS base; HW adds lane*16)
__device__ __forceinline__ void gload16(const void* g, void* l) {
    __builtin_amdgcn_global_load_lds(
        (const __attribute__((address_space(1))) unsigned int*)g,
        (__attribute__((address_space(3))) unsigned int*)l, 16, 0, 0);
}

// ---------------- CSR build ----------------

__global__ void k_count(const int* __restrict__ dst, int E, int* __restrict__ cnt) {
    int e = blockIdx.x * blockDim.x + threadIdx.x;
    if (e < E) atomicAdd(&cnt[dst[e]], 1);
}

__global__ void k_scan_sums(const int* __restrict__ cnt, int n, int* __restrict__ bsum) {
    __shared__ int s[256];
    int t = threadIdx.x;
    int base = blockIdx.x * 4096 + t * 16;
    int sum = 0;
#pragma unroll
    for (int j = 0; j < 16; ++j) { int i = base + j; if (i < n) sum += cnt[i]; }
    s[t] = sum;
    __syncthreads();
    for (int off = 128; off > 0; off >>= 1) {
        if (t < off) s[t] += s[t + off];
        __syncthreads();
    }
    if (t == 0) bsum[blockIdx.x] = s[0];
}

__global__ void k_scan_offsets(const int* __restrict__ bsum, int nb,
                               int* __restrict__ boff, int* __restrict__ totalp) {
    int t = threadIdx.x;   // 64 threads
    int v = (t < nb) ? bsum[t] : 0;
    int x = v;
    for (int off = 1; off < 64; off <<= 1) {
        int y = __shfl_up(x, off);
        if (t >= off) x += y;
    }
    if (t < nb) boff[t] = x - v;
    if (t == 63) *totalp = x;
}

// exclusive scan finish + dinv = rsqrt(cnt+1) (fused; cnt already in regs)
__global__ void k_scan_final(const int* __restrict__ cnt, int n,
                             const int* __restrict__ boff, int* __restrict__ row_ptr,
                             float* __restrict__ dinv) {
    __shared__ int s[256];
    int t = threadIdx.x;
    int base = blockIdx.x * 4096 + t * 16;
    int v[16]; int sum = 0;
#pragma unroll
    for (int j = 0; j < 16; ++j) { int i = base + j; v[j] = (i < n) ? cnt[i] : 0; sum += v[j]; }
    s[t] = sum;
    __syncthreads();
    for (int off = 1; off < 256; off <<= 1) {
        int y = (t >= off) ? s[t - off] : 0;
        __syncthreads();
        s[t] += y;
        __syncthreads();
    }
    int run = boff[blockIdx.x] + ((t == 0) ? 0 : s[t - 1]);
#pragma unroll
    for (int j = 0; j < 16; ++j) {
        int i = base + j;
        if (i < n) {
            row_ptr[i] = run;
            dinv[i] = rsqrtf((float)(v[j] + 1));
        }
        run += v[j];
    }
}

// fill CSR and the per-edge normalization weight norm = dinv[src]*dinv[dst]
__global__ void k_fill(const int* __restrict__ src, const int* __restrict__ dst, int E,
                       const int* __restrict__ row_ptr, int* __restrict__ cursor,
                       const float* __restrict__ dinv,
                       int* __restrict__ csr_src, float* __restrict__ csr_norm) {
    int e = blockIdx.x * blockDim.x + threadIdx.x;
    if (e >= E) return;
    int d = dst[e];
    int s = src[e];
    int p = atomicAdd(&cursor[d], 1);
    int slot = row_ptr[d] + p;
    csr_src[slot]  = s;
    csr_norm[slot] = dinv[s] * dinv[d];
}

// ------- fused weight pre-split: all 4 layers in one launch -------

__global__ void k_split_w_all(const float* __restrict__ w1, const float* __restrict__ w2,
                              const float* __restrict__ w3, const float* __restrict__ w4,
                              unsigned short* __restrict__ w1h, unsigned short* __restrict__ w1l,
                              unsigned short* __restrict__ w2h, unsigned short* __restrict__ w2l,
                              unsigned short* __restrict__ w3h, unsigned short* __restrict__ w3l,
                              unsigned short* __restrict__ w4h, unsigned short* __restrict__ w4l) {
    int idx = blockIdx.x * blockDim.x + threadIdx.x;
    const float* w; unsigned short *th, *tl; int N, ks, loc;
    if (idx < 131072)      { w = w1; th = w1h; tl = w1l; N = 256; ks = 9; loc = idx; }
    else if (idx < 163840) { w = w2; th = w2h; tl = w2l; N = 128; ks = 8; loc = idx - 131072; }
    else if (idx < 172032) { w = w3; th = w3h; tl = w3l; N = 64;  ks = 7; loc = idx - 163840; }
    else if (idx < 174080) { w = w4; th = w4h; tl = w4l; N = 32;  ks = 6; loc = idx - 172032; }
    else return;
    int nn = loc >> ks;
    int k  = loc & ((1 << ks) - 1);
    short2 p = split2(w[(size_t)k * N + nn]);
    th[loc] = (unsigned short)p.x;
    tl[loc] = (unsigned short)p.y;
}

// ---------------- layer-1 GEMM: dbuf + X 2-steps-ahead; bf16-plane epilogue ----------------

__global__ __launch_bounds__(256)
void k_gemm1(const float* __restrict__ A32,
             const unsigned short* __restrict__ Bth, const unsigned short* __restrict__ Btl,
             unsigned short* __restrict__ Chi, unsigned short* __restrict__ Clo, int M) {
    constexpr int K = 512, KT = 16;
    constexpr int APL = 128 * 64;   // 8KB per A plane
    constexpr int BPL = 128 * 64;
    __shared__ char sA[2][2 * APL];  // [buf][hi|lo]
    __shared__ char sB[2][2 * BPL];

    const int tid  = threadIdx.x;
    const int lane = tid & 63;
    const int w    = tid >> 6;
    const int wm   = w & 1;
    const int wn   = w >> 1;
    const int brow = blockIdx.y * 128;
    const int bcol = blockIdx.x * 128;
    const int l15  = lane & 15;
    const int kb   = (lane >> 4) * 16;

    const int arow  = tid >> 1;
    const int ahalf = tid & 1;
    int ag = brow + arow; if (ag > M - 1) ag = M - 1;   // clamp: dup rows only feed C rows >= M
    const float* xrow = A32 + (size_t)ag * K + ahalf * 16;
    const int vq = (arow >> 1) & 3;
    const int q0 = ((2 * ahalf) ^ vq) * 16;
    const int q1 = ((2 * ahalf + 1) ^ vq) * 16;

    f32x4 acc[4][4];
#pragma unroll
    for (int i = 0; i < 4; ++i)
#pragma unroll
        for (int j = 0; j < 4; ++j) acc[i][j] = (f32x4){0.f, 0.f, 0.f, 0.f};

    float4 xr[2][4];   // ping-pong X reg sets; loop fully unrolled -> static idx

    auto X = [&](int t, int p) {
        const float4* q = (const float4*)(xrow + t * 32);
        xr[p][0] = q[0]; xr[p][1] = q[1]; xr[p][2] = q[2]; xr[p][3] = q[3];
    };
    auto WA = [&](char* abuf, int p) {
        float v[16] = {xr[p][0].x, xr[p][0].y, xr[p][0].z, xr[p][0].w,
                       xr[p][1].x, xr[p][1].y, xr[p][1].z, xr[p][1].w,
                       xr[p][2].x, xr[p][2].y, xr[p][2].z, xr[p][2].w,
                       xr[p][3].x, xr[p][3].y, xr[p][3].z, xr[p][3].w};
        s16x8 h0, h1, l0, l1;
#pragma unroll
        for (int j = 0; j < 8; ++j) { short2 q = split2(v[j]);     h0[j] = q.x; l0[j] = q.y; }
#pragma unroll
        for (int j = 0; j < 8; ++j) { short2 q = split2(v[8 + j]); h1[j] = q.x; l1[j] = q.y; }
        *(s16x8*)(abuf + arow * 64 + q0)       = h0;
        *(s16x8*)(abuf + arow * 64 + q1)       = h1;
        *(s16x8*)(abuf + APL + arow * 64 + q0) = l0;
        *(s16x8*)(abuf + APL + arow * 64 + q1) = l1;
    };
    auto SB = [&](char* bbuf, int t) {
#pragma unroll
        for (int u = 0; u < 4; ++u) {
            int id = w + u * 4;                 // 0..15
            int hi = (id < 8) ? 1 : 0;
            int s  = hi ? id : id - 8;
            int p  = s * 64 + lane;
            int kq = (p ^ ((p >> 3) & 3)) & 3;
            int col = p >> 2;
            const unsigned short* gs = (hi ? Bth : Btl) + (size_t)(bcol + col) * K + t * 32 + kq * 8;
            gload16(gs, (hi ? bbuf : bbuf + BPL) + s * 1024);
        }
    };
    auto MM = [&](char* abuf, char* bbuf) {
        char* sAl = abuf + APL;
        char* sBl = bbuf + BPL;
        s16x8 fah[4], fam[4];
#pragma unroll
        for (int i = 0; i < 4; ++i) {
            int row = wm * 64 + i * 16 + l15;
            int o = row * 64 + (kb ^ (((row >> 1) & 3) << 4));
            fah[i] = *(const s16x8*)(abuf + o);
            fam[i] = *(const s16x8*)(sAl + o);
        }
#pragma unroll
        for (int j = 0; j < 4; ++j) {
            int col = wn * 64 + j * 16 + l15;
            int o = col * 64 + (kb ^ (((col >> 1) & 3) << 4));
            s16x8 fbh = *(const s16x8*)(bbuf + o);
            s16x8 fbm = *(const s16x8*)(sBl + o);
#pragma unroll
            for (int i = 0; i < 4; ++i) {
                acc[i][j] = __builtin_amdgcn_mfma_f32_16x16x32_bf16(fah[i], fbh, acc[i][j], 0, 0, 0);
                acc[i][j] = __builtin_amdgcn_mfma_f32_16x16x32_bf16(fam[i], fbh, acc[i][j], 0, 0, 0);
                acc[i][j] = __builtin_amdgcn_mfma_f32_16x16x32_bf16(fah[i], fbm, acc[i][j], 0, 0, 0);
            }
        }
    };

    // prologue
    X(0, 0);
    X(1, 1);
    SB(sB[0], 0);
    WA(sA[0], 0);
    __syncthreads();

#pragma unroll
    for (int t = 0; t < KT; ++t) {
        if (t + 2 < KT) X(t + 2, t & 1);
        if (t + 1 < KT) SB(sB[(t + 1) & 1], t + 1);
        MM(sA[t & 1], sB[t & 1]);
        if (t + 1 < KT) WA(sA[(t + 1) & 1], (t + 1) & 1);
        __syncthreads();
    }

    // C/D layout: col = lane&15, row = (lane>>4)*4 + reg; emit hi/lo planes
#pragma unroll
    for (int i = 0; i < 4; ++i) {
#pragma unroll
        for (int r = 0; r < 4; ++r) {
            int row = brow + wm * 64 + i * 16 + (lane >> 4) * 4 + r;
            if (row >= M) continue;
#pragma unroll
            for (int j = 0; j < 4; ++j) {
                int col = bcol + wn * 64 + j * 16 + l15;
                short2 pq = split2(acc[i][j][r]);
                Chi[(size_t)row * 256 + col] = (unsigned short)pq.x;
                Clo[(size_t)row * 256 + col] = (unsigned short)pq.y;
            }
        }
    }
}

// ---------------- generalized 2-phase dbuf split-bf16 MFMA GEMM (layers 2-4) ----------------
// BM=GM*FM*16 rows, BN=GN*FN*16 cols, 4 waves (GM x GN), BK=32.

template <int BM, int BN, int GM, int GN, int FM, int FN>
__global__ __launch_bounds__(256)
void k_gemm(const unsigned short* __restrict__ Ah, const unsigned short* __restrict__ Al,
            const unsigned short* __restrict__ Bth, const unsigned short* __restrict__ Btl,
            unsigned short* __restrict__ Chi, unsigned short* __restrict__ Clo,
            int M, int K, int N) {
    static_assert(GM * FM * 16 == BM && GN * FN * 16 == BN && GM * GN == 4, "geom");
    constexpr int ABYTES = BM * 64;          // one plane
    constexpr int BBYTES = BN * 64;
    constexpr int NSEGA = BM / 16;           // 1024B segments per plane
    constexpr int NSEGB = BN / 16;
    static_assert((2 * NSEGA) % 4 == 0 && (2 * NSEGB) % 4 == 0, "segs");
    constexpr int BUF = 2 * ABYTES + 2 * BBYTES;
    __shared__ char lds[2 * BUF];

    const int tid  = threadIdx.x;
    const int lane = tid & 63;
    const int w    = tid >> 6;
    const int wm   = w % GM;
    const int wn   = w / GM;
    const int brow = blockIdx.y * BM;
    const int bcol = blockIdx.x * BN;
    const int l15  = lane & 15;
    const int kb   = (lane >> 4) * 16;

    f32x4 acc[FM][FN];
#pragma unroll
    for (int i = 0; i < FM; ++i)
#pragma unroll
        for (int j = 0; j < FN; ++j) acc[i][j] = (f32x4){0.f, 0.f, 0.f, 0.f};

    auto stageA = [&](char* base, int k0) {
#pragma unroll
        for (int u = 0; u < (2 * NSEGA) / 4; ++u) {
            int id = w + u * 4;
            int hi = (id < NSEGA) ? 1 : 0;
            int s  = hi ? id : id - NSEGA;
            int p  = s * 64 + lane;
            int kq = (p ^ ((p >> 3) & 3)) & 3;
            int row = p >> 2;
            const unsigned short* gs = (hi ? Ah : Al) + (size_t)(brow + row) * K + k0 + kq * 8;
            gload16(gs, base + (hi ? 0 : ABYTES) + s * 1024);
        }
    };
    auto stageB = [&](char* base, int k0) {
        char* sBh = base + 2 * ABYTES;
        char* sBl = sBh + BBYTES;
#pragma unroll
        for (int u = 0; u < (2 * NSEGB) / 4; ++u) {
            int id = w + u * 4;
            int hi = (id < NSEGB) ? 1 : 0;
            int s  = hi ? id : id - NSEGB;
            int p  = s * 64 + lane;
            int kq = (p ^ ((p >> 3) & 3)) & 3;
            int col = p >> 2;
            const unsigned short* gs = (hi ? Bth : Btl) + (size_t)(bcol + col) * K + k0 + kq * 8;
            gload16(gs, (hi ? sBh : sBl) + s * 1024);
        }
    };

    char* cur = lds;
    char* nxt = lds + BUF;
    stageB(cur, 0);
    stageA(cur, 0);
    __syncthreads();

    const int KT = K / 32;
    for (int t = 0; t < KT; ++t) {
        const int k1 = (t + 1) * 32;
        if (t + 1 < KT) {
            stageB(nxt, k1);
            stageA(nxt, k1);
        }
        {
            char* sAh = cur;
            char* sAl = cur + ABYTES;
            char* sBh = cur + 2 * ABYTES;
            char* sBl = sBh + BBYTES;
            s16x8 fah[FM], fam[FM];
#pragma unroll
            for (int i = 0; i < FM; ++i) {
                int row = wm * FM * 16 + i * 16 + l15;
                int o = row * 64 + (kb ^ (((row >> 1) & 3) << 4));
                fah[i] = *(const s16x8*)(sAh + o);
                fam[i] = *(const s16x8*)(sAl + o);
            }
#pragma unroll
            for (int j = 0; j < FN; ++j) {
                int col = wn * FN * 16 + j * 16 + l15;
                int o = col * 64 + (kb ^ (((col >> 1) & 3) << 4));
                s16x8 fbh = *(const s16x8*)(sBh + o);
                s16x8 fbm = *(const s16x8*)(sBl + o);
#pragma unroll
                for (int i = 0; i < FM; ++i) {
                    acc[i][j] = __builtin_amdgcn_mfma_f32_16x16x32_bf16(fah[i], fbh, acc[i][j], 0, 0, 0);
                    acc[i][j] = __builtin_amdgcn_mfma_f32_16x16x32_bf16(fam[i], fbh, acc[i][j], 0, 0, 0);
                    acc[i][j] = __builtin_amdgcn_mfma_f32_16x16x32_bf16(fah[i], fbm, acc[i][j], 0, 0, 0);
                }
            }
        }
        __syncthreads();
        char* tmp = cur; cur = nxt; nxt = tmp;
    }

#pragma unroll
    for (int i = 0; i < FM; ++i) {
#pragma unroll
        for (int r = 0; r < 4; ++r) {
            int row = brow + wm * FM * 16 + i * 16 + (lane >> 4) * 4 + r;
            if (row >= M) continue;
#pragma unroll
            for (int j = 0; j < FN; ++j) {
                int col = bcol + wn * FN * 16 + j * 16 + l15;
                short2 pq = split2(acc[i][j][r]);
                Chi[(size_t)row * N + col] = (unsigned short)pq.x;
                Clo[(size_t)row * N + col] = (unsigned short)pq.y;
            }
        }
    }
}

// ---------------- aggregation (+bias, relu) -> bf16 hi/lo planes ----------------
// out[i] = di^2*h[i](hi+lo) + sum_e norm[e]*hi(h[src[e]]) + b

__global__ void k_agg_split(const unsigned short* __restrict__ hhi,
                            const unsigned short* __restrict__ hlo,
                            const int* __restrict__ row_ptr,
                            const int* __restrict__ csr_src, const float* __restrict__ csr_norm,
                            const float* __restrict__ dinv, const float* __restrict__ bias,
                            unsigned short* __restrict__ oh, unsigned short* __restrict__ ol,
                            int n, int f_shift) {
    int idx = blockIdx.x * blockDim.x + threadIdx.x;
    int dout4 = 1 << f_shift;
    int total = n << f_shift;
    if (idx >= total) return;
    int i = idx >> f_shift;
    int f = idx & (dout4 - 1);
    const int drow = dout4 * 4;
    size_t ebase = (size_t)i * drow + f * 4;

    float di = dinv[i];
    float sn = di * di;
    ushort4 sh = *(const ushort4*)(hhi + ebase);
    ushort4 sl = *(const ushort4*)(hlo + ebase);
    float4 acc;
    acc.x = (bf2f(sh.x) + bf2f(sl.x)) * sn;
    acc.y = (bf2f(sh.y) + bf2f(sl.y)) * sn;
    acc.z = (bf2f(sh.z) + bf2f(sl.z)) * sn;
    acc.w = (bf2f(sh.w) + bf2f(sl.w)) * sn;

    int e = row_ptr[i], s1 = row_ptr[i + 1];
    for (; e + 1 < s1; e += 2) {
        int   sa = csr_src[e],      sb = csr_src[e + 1];
        float na = csr_norm[e],     nb = csr_norm[e + 1];
        ushort4 va = *(const ushort4*)(hhi + (size_t)sa * drow + f * 4);
        ushort4 vb = *(const ushort4*)(hhi + (size_t)sb * drow + f * 4);
        acc.x += bf2f(va.x) * na + bf2f(vb.x) * nb;
        acc.y += bf2f(va.y) * na + bf2f(vb.y) * nb;
        acc.z += bf2f(va.z) * na + bf2f(vb.z) * nb;
        acc.w += bf2f(va.w) * na + bf2f(vb.w) * nb;
    }
    if (e < s1) {
        int   s = csr_src[e];
        float nm = csr_norm[e];
        ushort4 v = *(const ushort4*)(hhi + (size_t)s * drow + f * 4);
        acc.x += bf2f(v.x) * nm; acc.y += bf2f(v.y) * nm;
        acc.z += bf2f(v.z) * nm; acc.w += bf2f(v.w) * nm;
    }

    const float4* b4 = (const float4*)bias;
    float4 b = b4[f];
    float4 o;
    o.x = fmaxf(acc.x + b.x, 0.f);
    o.y = fmaxf(acc.y + b.y, 0.f);
    o.z = fmaxf(acc.z + b.z, 0.f);
    o.w = fmaxf(acc.w + b.w, 0.f);

    short2 p0 = split2(o.x), p1 = split2(o.y), p2 = split2(o.z), p3 = split2(o.w);
    *(ushort4*)(oh + ebase) = make_ushort4((unsigned short)p0.x, (unsigned short)p1.x,
                                           (unsigned short)p2.x, (unsigned short)p3.x);
    *(ushort4*)(ol + ebase) = make_ushort4((unsigned short)p0.y, (unsigned short)p1.y,
                                           (unsigned short)p2.y, (unsigned short)p3.y);
}

// ---------------- aggregation (+bias), fp32 out (layer 4) ----------------

__global__ void k_agg(const unsigned short* __restrict__ hhi,
                      const unsigned short* __restrict__ hlo,
                      const int* __restrict__ row_ptr,
                      const int* __restrict__ csr_src, const float* __restrict__ csr_norm,
                      const float* __restrict__ dinv, const float* __restrict__ bias,
                      float4* __restrict__ out, int n, int f_shift) {
    int idx = blockIdx.x * blockDim.x + threadIdx.x;
    int dout4 = 1 << f_shift;
    int total = n << f_shift;
    if (idx >= total) return;
    int i = idx >> f_shift;
    int f = idx & (dout4 - 1);
    const int drow = dout4 * 4;
    size_t ebase = (size_t)i * drow + f * 4;

    float di = dinv[i];
    float sn = di * di;
    ushort4 sh = *(const ushort4*)(hhi + ebase);
    ushort4 sl = *(const ushort4*)(hlo + ebase);
    float4 acc;
    acc.x = (bf2f(sh.x) + bf2f(sl.x)) * sn;
    acc.y = (bf2f(sh.y) + bf2f(sl.y)) * sn;
    acc.z = (bf2f(sh.z) + bf2f(sl.z)) * sn;
    acc.w = (bf2f(sh.w) + bf2f(sl.w)) * sn;

    int e = row_ptr[i], s1 = row_ptr[i + 1];
    for (; e + 1 < s1; e += 2) {
        int   sa = csr_src[e],      sb = csr_src[e + 1];
        float na = csr_norm[e],     nb = csr_norm[e + 1];
        ushort4 va = *(const ushort4*)(hhi + (size_t)sa * drow + f * 4);
        ushort4 vb = *(const ushort4*)(hhi + (size_t)sb * drow + f * 4);
        acc.x += bf2f(va.x) * na + bf2f(vb.x) * nb;
        acc.y += bf2f(va.y) * na + bf2f(vb.y) * nb;
        acc.z += bf2f(va.z) * na + bf2f(vb.z) * nb;
        acc.w += bf2f(va.w) * na + bf2f(vb.w) * nb;
    }
    if (e < s1) {
        int   s = csr_src[e];
        float nm = csr_norm[e];
        ushort4 v = *(const ushort4*)(hhi + (size_t)s * drow + f * 4);
        acc.x += bf2f(v.x) * nm; acc.y += bf2f(v.y) * nm;
        acc.z += bf2f(v.z) * nm; acc.w += bf2f(v.w) * nm;
    }

    const float4* b4 = (const float4*)bias;
    float4 b = b4[f];
    float4 o;
    o.x = acc.x + b.x;
    o.y = acc.y + b.y;
    o.z = acc.z + b.z;
    o.w = acc.w + b.w;
    out[(size_t)i * dout4 + f] = o;
}

// ---------------- mean pool per graph (batch sorted) ----------------

__global__ void k_pool(const float* __restrict__ h, const int* __restrict__ batch,
                       int n, float* __restrict__ pooled) {
    int g = blockIdx.x;
    int start, end;
    {
        int lo = 0, hi = n;
        while (lo < hi) { int mid = (lo + hi) >> 1; if (batch[mid] < g) lo = mid + 1; else hi = mid; }
        start = lo;
        lo = start; hi = n;
        while (lo < hi) { int mid = (lo + hi) >> 1; if (batch[mid] < g + 1) lo = mid + 1; else hi = mid; }
        end = lo;
    }
    int f = threadIdx.x & 31;
    int sub = threadIdx.x >> 5;
    float s = 0.f;
    for (int i = start + sub; i < end; i += 8) s += h[(size_t)i * 32 + f];
    __shared__ float red[8][32];
    red[sub][f] = s;
    __syncthreads();
    if (sub == 0) {
        float t = 0.f;
#pragma unroll
        for (int k = 0; k < 8; ++k) t += red[k][f];
        int c = end - start;
        pooled[g * 32 + f] = t / (float)(c > 0 ? c : 1);
    }
}

// ---------------- tiny MLP head ----------------

__global__ void k_mlp(const float* __restrict__ pooled, const float* __restrict__ lw1,
                      const float* __restrict__ lb1, const float* __restrict__ lw2,
                      const float* __restrict__ lb2, float* __restrict__ out, int g_count) {
    int g = threadIdx.x;
    if (g >= g_count) return;
    float p[32];
#pragma unroll
    for (int k = 0; k < 32; ++k) p[k] = pooled[g * 32 + k];
    float hmid[16];
#pragma unroll
    for (int j = 0; j < 16; ++j) {
        float s = lb1[j];
#pragma unroll
        for (int k = 0; k < 32; ++k) s += p[k] * lw1[k * 16 + j];
        hmid[j] = fmaxf(s, 0.f);
    }
#pragma unroll
    for (int o = 0; o < 2; ++o) {
        float s = lb2[o];
#pragma unroll
        for (int k = 0; k < 16; ++k) s += hmid[k] * lw2[k * 2 + o];
        out[g * 2 + o] = s;
    }
}

// ---------------- launch ----------------

extern "C" void kernel_launch(void* const* d_in, const int* in_sizes, int n_in,
                              void* d_out, int out_size, void* d_ws, size_t ws_size,
                              hipStream_t stream) {
    const float* x     = (const float*)d_in[0];
    const int*   ei    = (const int*)d_in[1];
    const int*   batch = (const int*)d_in[2];
    const float* w1 = (const float*)d_in[3];  const float* b1 = (const float*)d_in[4];
    const float* w2 = (const float*)d_in[5];  const float* b2 = (const float*)d_in[6];
    const float* w3 = (const float*)d_in[7];  const float* b3 = (const float*)d_in[8];
    const float* w4 = (const float*)d_in[9];  const float* b4 = (const float*)d_in[10];
    const float* lw1 = (const float*)d_in[11]; const float* lb1 = (const float*)d_in[12];
    const float* lw2 = (const float*)d_in[13]; const float* lb2 = (const float*)d_in[14];
    float* out = (float*)d_out;

    const int n = in_sizes[0] / 512;   // 100000
    const int E = in_sizes[1] / 2;     // 320000
    const int G = 64;

    const int* src = ei;
    const int* dst = ei + E;

    char* ws = (char*)d_ws;
    size_t off = 0;
    auto alloc = [&](size_t bytes) -> void* {
        void* p = ws + off;
        off = (off + bytes + 255) & ~((size_t)255);
        return p;
    };
    unsigned short* ghi  = (unsigned short*)alloc((size_t)n * 256 * 2);  // GEMM out hi plane
    unsigned short* glo  = (unsigned short*)alloc((size_t)n * 256 * 2);  // GEMM out lo plane
    unsigned short* pAh  = (unsigned short*)alloc((size_t)n * 256 * 2);  // agg-out planes
    unsigned short* pAl  = (unsigned short*)alloc((size_t)n * 256 * 2);
    int*   cnt      = (int*)alloc((size_t)n * sizeof(int));
    int*   cursor   = (int*)alloc((size_t)n * sizeof(int));
    int*   row_ptr  = (int*)alloc((size_t)(n + 1) * sizeof(int));
    int*   csr      = (int*)alloc((size_t)E * sizeof(int));
    float* csr_norm = (float*)alloc((size_t)E * sizeof(float));
    float* dinv     = (float*)alloc((size_t)n * sizeof(float));
    float* pooled   = (float*)alloc((size_t)G * 32 * sizeof(float));
    int*   bsum     = (int*)alloc(64 * sizeof(int));
    int*   boff     = (int*)alloc(64 * sizeof(int));
    unsigned short* w1h = (unsigned short*)alloc(256 * 512 * 2);
    unsigned short* w1l = (unsigned short*)alloc(256 * 512 * 2);
    unsigned short* w2h = (unsigned short*)alloc(128 * 256 * 2);
    unsigned short* w2l = (unsigned short*)alloc(128 * 256 * 2);
    unsigned short* w3h = (unsigned short*)alloc(64 * 128 * 2);
    unsigned short* w3l = (unsigned short*)alloc(64 * 128 * 2);
    unsigned short* w4h = (unsigned short*)alloc(32 * 64 * 2);
    unsigned short* w4l = (unsigned short*)alloc(32 * 64 * 2);
    // layer-4 fp32 agg output parked in pAl beyond the live d=64 plane region
    float* bufB = (float*)(pAl + (size_t)n * 64);
    (void)ws_size;

    // NOTE: n*sizeof(int) is NOT a 256B multiple — zero each separately (r11 lesson).
    hipMemsetAsync(cnt, 0, (size_t)n * sizeof(int), stream);
    hipMemsetAsync(cursor, 0, (size_t)n * sizeof(int), stream);

    // fused weight pre-split (1 launch)
    k_split_w_all<<<(174080 + 255) / 256, 256, 0, stream>>>(
        w1, w2, w3, w4, w1h, w1l, w2h, w2l, w3h, w3l, w4h, w4l);

    const int nscan = (n + 4095) / 4096;
    k_count<<<(E + 255) / 256, 256, 0, stream>>>(dst, E, cnt);
    k_scan_sums   <<<nscan, 256, 0, stream>>>(cnt, n, bsum);
    k_scan_offsets<<<1, 64, 0, stream>>>(bsum, nscan, boff, row_ptr + n);
    k_scan_final  <<<nscan, 256, 0, stream>>>(cnt, n, boff, row_ptr, dinv);
    k_fill<<<(E + 255) / 256, 256, 0, stream>>>(src, dst, E, row_ptr, cursor, dinv, csr, csr_norm);

    const int gy128 = (n + 127) / 128;   // 782
    const int gy64  = (n + 63) / 64;     // 1563

    // layer 1: [n,512]@[512,256], BM=128/BN=128, dbuf + X-2-ahead, x split in-kernel
    k_gemm1<<<dim3(2, gy128), 256, 0, stream>>>(x, w1h, w1l, ghi, glo, n);
    k_agg_split<<<((size_t)n * 64 + 255) / 256, 256, 0, stream>>>(
        ghi, glo, row_ptr, csr, csr_norm, dinv, b1, pAh, pAl, n, 6);

    // layer 2: [n,256]@[256,128], BM=64 (1563 blocks, 48KB LDS)
    k_gemm<64, 128, 1, 4, 4, 2><<<dim3(1, gy64), 256, 0, stream>>>(
        pAh, pAl, w2h, w2l, ghi, glo, n, 256, 128);
    k_agg_split<<<((size_t)n * 32 + 255) / 256, 256, 0, stream>>>(
        ghi, glo, row_ptr, csr, csr_norm, dinv, b2, pAh, pAl, n, 5);

    // layer 3: [n,128]@[128,64], BM=64 (32KB LDS)
    k_gemm<64, 64, 1, 4, 4, 1><<<dim3(1, gy64), 256, 0, stream>>>(
        pAh, pAl, w3h, w3l, ghi, glo, n, 128, 64);
    k_agg_split<<<((size_t)n * 16 + 255) / 256, 256, 0, stream>>>(
        ghi, glo, row_ptr, csr, csr_norm, dinv, b3, pAh, pAl, n, 4);

    // layer 4: [n,64]@[64,32], BM=64 (24KB LDS, no relu)
    k_gemm<64, 32, 2, 2, 2, 1><<<dim3(1, gy64), 256, 0, stream>>>(
        pAh, pAl, w4h, w4l, ghi, glo, n, 64, 32);
    k_agg<<<((size_t)n * 8 + 255) / 256, 256, 0, stream>>>(
        ghi, glo, row_ptr, csr, csr_norm, dinv, b4, (float4*)bufB, n, 3);

    k_pool<<<G, 256, 0, stream>>>(bufB, batch, n, pooled);
    k_mlp<<<1, 64, 0, stream>>>(pooled, lw1, lb1, lw2, lb2, out, G);
}